// Round 18
// baseline (358.975 us; speedup 1.0000x reference)
//
#include <hip/hip_runtime.h>

typedef __attribute__((ext_vector_type(4))) float f32x4;
typedef __attribute__((ext_vector_type(8))) int i32x8;
typedef __attribute__((ext_vector_type(4))) long l64x4;

#define AS1(p) ((const __attribute__((address_space(1))) void*)(p))
#define AS3(p) ((__attribute__((address_space(3))) void*)(p))

__device__ __forceinline__ unsigned short f2bf(float f) {
  unsigned u = __builtin_bit_cast(unsigned, f);
  u += 0x7fffu + ((u >> 16) & 1u);
  return (unsigned short)(u >> 16);
}
// fp32 -> OCP e4m3fn (RNE, FTZ below 2^-6, clamp 448)
__device__ __forceinline__ unsigned f2e4m3(float f) {
  unsigned uf = __builtin_bit_cast(unsigned, f);
  unsigned s = (uf >> 24) & 0x80u;
  unsigned u = uf & 0x7fffffffu;
  if (u < 0x3c800000u) return s;
  if (u > 0x43e00000u) u = 0x43e00000u;
  u += 0x7ffffu + ((u >> 20) & 1u);
  unsigned v = (u >> 20) - 960u;
  if (v > 126u) v = 126u;
  return s | v;
}

// Global pre-swizzle rule for fp8 GEMM operands (verified r15: conflicts 1.9e7->98K):
//   phys_k = (k & ~127) | ((k & 127) ^ ((row & 15) << 3))
// r18: MX-scaled MFMA 16x16x128 (2x fp8 rate), scales pinned to 1.0 (e8m0=127).
// Per-lane operand = 32 contiguous logical K-bytes at k=fk*32, read as 4 b64 at
// (fk*32 + j*8)^xr — slot (fk*4+j)^fr bijective per 16-lane phase = conflict-free.

// ---------------- fused prep: W1/W2 fp8 casts + chunkmax + w2_fold ----------------
__global__ __launch_bounds__(256) void prep(const float* __restrict__ W1,
                                            unsigned char* __restrict__ W1q,
                                            const float* __restrict__ W2,
                                            unsigned char* __restrict__ W2q,
                                            const float* __restrict__ x,
                                            float* __restrict__ partial,
                                            const float* __restrict__ lnw,
                                            const float* __restrict__ lnb,
                                            float* __restrict__ w2l,
                                            float* __restrict__ b2l) {
  __shared__ float ss[4], bb[4];
  const int bid = blockIdx.x;
  if (bid < 1536) {
    long i = ((long)bid * 256 + threadIdx.x) * 4;
    const long n1 = (long)4096 * 3072;
    const long stride = (long)1536 * 256 * 4;
    for (; i < n1; i += stride) {
      float4 f = *(const float4*)(W1 + i);
      unsigned v = f2e4m3(f.x * 32.f) | (f2e4m3(f.y * 32.f) << 8) |
                   (f2e4m3(f.z * 32.f) << 16) | (f2e4m3(f.w * 32.f) << 24);
      long n = i / 3072;
      long k = i - n * 3072;
      long phys = n * 3072 + (k & ~(long)127) + ((k & 127) ^ ((n & 15) << 3));
      *(unsigned*)(W1q + phys) = v;
    }
  } else if (bid < 2048) {
    long i = ((long)(bid - 1536) * 256 + threadIdx.x) * 4;
    const long n2 = (long)1024 * 4096;
    const long stride = (long)512 * 256 * 4;
    for (; i < n2; i += stride) {
      float4 f = *(const float4*)(W2 + i);
      unsigned v = f2e4m3(f.x * 32.f) | (f2e4m3(f.y * 32.f) << 8) |
                   (f2e4m3(f.z * 32.f) << 16) | (f2e4m3(f.w * 32.f) << 24);
      long n = i >> 12;
      long k = i & 4095;
      long phys = (n << 12) + (k & ~(long)127) + ((k & 127) ^ ((n & 15) << 3));
      *(unsigned*)(W2q + phys) = v;
    }
  } else if (bid < 2560) {
    const int b = bid - 2048;
    const int col = (b & 3) * 256 + threadIdx.x;
    const int chunk = b >> 2;
    const float* p = x + (long)chunk * 64 * 1024 + col;
    float m = -INFINITY;
#pragma unroll 4
    for (int i = 0; i < 64; i++) m = fmaxf(m, p[(long)i * 1024]);
    partial[chunk * 1024 + col] = m;
  } else {
    const int n = bid - 2560;
    const float* w = W2 + (long)n * 4096;
    float s = 0.f, b = 0.f;
    for (int k = threadIdx.x; k < 4096; k += 256) {
      float wv = w[k];
      s += wv * lnw[k];
      b += wv * lnb[k];
    }
#pragma unroll
    for (int off = 32; off; off >>= 1) {
      s += __shfl_xor(s, off, 64);
      b += __shfl_xor(b, off, 64);
    }
    const int wv2 = threadIdx.x >> 6;
    if ((threadIdx.x & 63) == 0) { ss[wv2] = s; bb[wv2] = b; }
    __syncthreads();
    if (threadIdx.x == 0) {
      w2l[n] = ss[0] + ss[1] + ss[2] + ss[3];
      b2l[n] = bb[0] + bb[1] + bb[2] + bb[3];
    }
  }
}

// ---------------- scan_emit with inline chunk-scan: h_in fp8 pre-swizzled ----------------
__global__ __launch_bounds__(256) void scan_emit(const float* __restrict__ x,
                                                 const float* __restrict__ partial,
                                                 unsigned char* __restrict__ h_in) {
  const int col = blockIdx.x * 256 + threadIdx.x;
  const int chunk = blockIdx.y;
  float pre = -INFINITY, suf = -INFINITY;
#pragma unroll
  for (int c = 0; c < 128; ++c) {
    float pv = partial[c * 1024 + col];
    if (c < chunk) pre = fmaxf(pre, pv);
    if (c > chunk) suf = fmaxf(suf, pv);
  }
  long r0 = (long)chunk * 64;
  const int cb = col & ~127, cw = col & 127;
  float run = pre;
  for (int i = 0; i < 64; i++) {
    long row = r0 + i;
    int xo = (int)(row & 15) << 3;
    int c0 = cb | (cw ^ xo);
    float v = x[row * 1024 + col];
    unsigned char* hr = h_in + row * 3072;
    hr[c0] = (unsigned char)f2e4m3(v);
    hr[1024 + c0] = (unsigned char)(row == 0 ? 0u : f2e4m3(run));
    run = fmaxf(run, v);
  }
  float run2 = suf;
  for (int i = 63; i >= 0; i--) {
    long row = r0 + i;
    int xo = (int)(row & 15) << 3;
    int c0 = cb | (cw ^ xo);
    float v = x[row * 1024 + col];
    h_in[row * 3072 + 2048 + c0] = (unsigned char)(row == 8191 ? 0u : f2e4m3(run2));
    run2 = fmaxf(run2, v);
  }
}

#define MFMA_SC(dst, a_, b_)                                                   \
  dst = __builtin_amdgcn_mfma_scale_f32_16x16x128_f8f6f4(                      \
      __builtin_bit_cast(i32x8, a_), __builtin_bit_cast(i32x8, b_), dst,       \
      0, 0, 0, 0x7f7f7f7f, 0, 0x7f7f7f7f);

// ============ 256x256 FP8 GEMM1, BK=128, MX-scaled MFMA (r18) ============
__global__ __launch_bounds__(512, 2) void gemm256_relu(
    const unsigned char* __restrict__ A, const unsigned char* __restrict__ B,
    unsigned char* __restrict__ C, const float* __restrict__ bias,
    const float* __restrict__ lnw, float* __restrict__ pp,
    int M, int N, int K) {
  extern __shared__ char smem[];
  const int NT = K >> 7;

  const int nwg = gridDim.x;
  const int cpx = nwg >> 3;
  const int bid = blockIdx.x;
  const int swz = (bid & 7) * cpx + (bid >> 3);
  const int tiles_m = M >> 8;
  const int tm = swz % tiles_m;
  const int tn = swz / tiles_m;
  const long brow = (long)tm * 256;
  const long bcol = (long)tn * 256;

  const int t = threadIdx.x;
  const int lane = t & 63, wv = t >> 6;
  const int wr = wv >> 2, wc = wv & 3;
  const int fr = lane & 15, fk = lane >> 4;

  const int srow = t >> 3;
  const int scol = (t & 7) * 16;
  const unsigned char* Asrc = A + (brow + srow) * (long)K + scol;
  const unsigned char* Bsrc = B + (bcol + srow) * (long)K + scol;
  const long hstep = (long)128 * K, lstep = (long)64 * K;

#define STAGE_A(j, reg, h, L)                                                   \
  __builtin_amdgcn_global_load_lds(AS1(Asrc + (h)*hstep + (L)*lstep + (j)*128), \
      AS3(smem + (reg)*32768 + (h)*16384 + (L)*8192 + t * 16), 16, 0, 0)
#define STAGE_B(j, h, L)                                                        \
  __builtin_amdgcn_global_load_lds(AS1(Bsrc + (h)*hstep + (L)*lstep + (j)*128), \
      AS3(smem + 98304 + ((j)&1) * 32768 + (h)*16384 + (L)*8192 + t * 16), 16, 0, 0)

  const int xr = fr << 3;
  const char* ArdRow = smem + (wr * 128 + fr) * 128;
  const char* BrdRow = smem + 98304 + (wc * 64 + fr) * 128;
  // per-lane 32 contiguous logical K-bytes at k = fk*32, as 4 b64 (j = 0..3)
#define RD_A(ar_, m, j) \
  (*(const long*)(ArdRow + (ar_)*32768 + (m)*2048 + ((fk * 32 + (j)*8) ^ xr)))
#define RD_B(pb_, n, j) \
  (*(const long*)(BrdRow + (pb_)*32768 + (n)*2048 + ((fk * 32 + (j)*8) ^ xr)))

  f32x4 acc[8][4];
#pragma unroll
  for (int m = 0; m < 8; m++)
#pragma unroll
    for (int n = 0; n < 4; n++) acc[m][n] = (f32x4)0.f;

  STAGE_A(0, 0, 0, 0); STAGE_A(0, 0, 0, 1); STAGE_A(0, 0, 1, 0); STAGE_A(0, 0, 1, 1);
  STAGE_B(0, 0, 0); STAGE_B(0, 0, 1); STAGE_B(0, 1, 0); STAGE_B(0, 1, 1);
  STAGE_A(1, 1, 0, 0); STAGE_A(1, 1, 0, 1); STAGE_A(1, 1, 1, 0); STAGE_A(1, 1, 1, 1);
  STAGE_B(1, 0, 0); STAGE_B(1, 0, 1); STAGE_B(1, 1, 0); STAGE_B(1, 1, 1);
  asm volatile("s_waitcnt vmcnt(8)" ::: "memory");
  __builtin_amdgcn_s_barrier();

  l64x4 bfr[4];
  l64x4 ap[2][2];  // [set][i]
#pragma unroll
  for (int j = 0; j < 4; ++j) {
    ap[0][0][j] = RD_A(0, 0, j);
    ap[0][1][j] = RD_A(0, 1, j);
  }

  int ar = 0;
  for (int g = 0; g < NT; ++g) {
    const int pb = g & 1;
    int sr = ar + 2; if (sr >= 3) sr -= 3;
    int nar = ar + 1; if (nar >= 3) nar = 0;
    const bool st = (g + 2 < NT);
#pragma unroll
    for (int p = 0; p < 4; ++p) {
      const int cs = p & 1, ns = cs ^ 1;
      if (p == 0) {
#pragma unroll
        for (int n = 0; n < 4; ++n)
#pragma unroll
          for (int j = 0; j < 4; ++j) bfr[n][j] = RD_B(pb, n, j);
      }
      asm volatile("s_waitcnt lgkmcnt(0)" ::: "memory");
      __builtin_amdgcn_sched_barrier(0);
      __builtin_amdgcn_s_setprio(1);
#pragma unroll
      for (int n = 0; n < 4; ++n) {
        MFMA_SC(acc[2 * p][n], ap[cs][0], bfr[n])
        MFMA_SC(acc[2 * p + 1][n], ap[cs][1], bfr[n])
      }
      __builtin_amdgcn_s_setprio(0);
      if (p < 3) {
#pragma unroll
        for (int j = 0; j < 4; ++j) {
          ap[ns][0][j] = RD_A(ar, 2 * p + 2, j);
          ap[ns][1][j] = RD_A(ar, 2 * p + 3, j);
        }
      } else if (g + 1 < NT) {
#pragma unroll
        for (int j = 0; j < 4; ++j) {
          ap[ns][0][j] = RD_A(nar, 0, j);
          ap[ns][1][j] = RD_A(nar, 1, j);
        }
      }
      if (st) {
        if (p == 0) { STAGE_A(g + 2, sr, 0, 0); STAGE_A(g + 2, sr, 0, 1); }
        if (p == 1) { STAGE_A(g + 2, sr, 1, 0); STAGE_A(g + 2, sr, 1, 1); }
        if (p == 2) { STAGE_B(g + 2, 0, 0); STAGE_B(g + 2, 0, 1); }
        if (p == 3) { STAGE_B(g + 2, 1, 0); STAGE_B(g + 2, 1, 1); }
      }
      if (p == 2 && g + 1 < NT) {
        if (st) asm volatile("s_waitcnt vmcnt(6)" ::: "memory");
        else    asm volatile("s_waitcnt vmcnt(0)" ::: "memory");
      }
      asm volatile("s_barrier" ::: "memory");
    }
    ar = nar;
  }

  float bi[4], lw[4];
#pragma unroll
  for (int n = 0; n < 4; ++n) {
    const long col = bcol + wc * 64 + n * 16 + fr;
    bi[n] = bias[col];
    lw[n] = lnw[col];
  }
  float* sred = (float*)smem;
  float* qred = sred + 1024;
  const long orow = brow + wr * 128 + fk * 4;
  const int ocol = (int)bcol + wc * 64 + fr;
#pragma unroll
  for (int m = 0; m < 8; ++m) {
#pragma unroll
    for (int r = 0; r < 4; ++r) {
      const long row = orow + m * 16 + r;
      const int xo = ((fk * 4 + r) & 15) << 3;
      float s = 0.f, q = 0.f;
#pragma unroll
      for (int n = 0; n < 4; ++n) {
        float v = acc[m][n][r] * 0.03125f + bi[n];
        v = v > 0.f ? v : 0.f;
        s += v;
        q += v * v;
        const int col = ocol + n * 16;
        const int phys = (col & ~127) | ((col & 127) ^ xo);
        C[row * (long)N + phys] = (unsigned char)f2e4m3(v * lw[n]);
      }
#pragma unroll
      for (int off = 1; off < 16; off <<= 1) {
        s += __shfl_xor(s, off, 64);
        q += __shfl_xor(q, off, 64);
      }
      if (fr == 0) {
        int rl = wr * 128 + m * 16 + fk * 4 + r;
        sred[rl * 4 + wc] = s;
        qred[rl * 4 + wc] = q;
      }
    }
  }
  __syncthreads();
  if (t < 256) {
    float s = sred[t * 4] + sred[t * 4 + 1] + sred[t * 4 + 2] + sred[t * 4 + 3];
    float q = qred[t * 4] + qred[t * 4 + 1] + qred[t * 4 + 2] + qred[t * 4 + 3];
    float* pb = pp + (((long)(tm * 16 + tn) * 256 + t) * 2);
    pb[0] = s;
    pb[1] = q;
  }
#undef STAGE_A
#undef STAGE_B
#undef RD_A
#undef RD_B
}

// ============ 256x128 FP8 GEMM2, BK=128, MX-scaled MFMA (r18; stats fused) ============
__global__ __launch_bounds__(512, 2) void gemm256_g2(
    const unsigned char* __restrict__ A, const unsigned char* __restrict__ B,
    float* __restrict__ Cf, const float* __restrict__ bias,
    const float* __restrict__ gamma, const float* __restrict__ resid,
    const float* __restrict__ w2l, const float* __restrict__ b2l,
    const float* __restrict__ pp,
    int M, int N, int K) {
  extern __shared__ char smem[];
  const int NT = K >> 7;

  const int nwg = gridDim.x;
  const int cpx = nwg >> 3;
  const int bid = blockIdx.x;
  const int swz = (bid & 7) * cpx + (bid >> 3);
  const int tiles_m = M >> 8;
  const int tm = swz % tiles_m;
  const int tn = swz / tiles_m;
  const long brow = (long)tm * 256;
  const long bcol = (long)tn * 128;

  const int t = threadIdx.x;
  const int lane = t & 63, wv = t >> 6;
  const int wr = wv >> 1, wc = wv & 1;
  const int fr = lane & 15, fk = lane >> 4;

  const int srow = t >> 3;
  const int scol = (t & 7) * 16;
  const unsigned char* Asrc = A + (brow + srow) * (long)K + scol;
  const unsigned char* Bsrc = B + (bcol + srow) * (long)K + scol;
  const long hstep = (long)128 * K, lstep = (long)64 * K;

#define STAGE_A2(j, reg, h, L)                                                  \
  __builtin_amdgcn_global_load_lds(AS1(Asrc + (h)*hstep + (L)*lstep + (j)*128), \
      AS3(smem + (reg)*32768 + (h)*16384 + (L)*8192 + t * 16), 16, 0, 0)
#define STAGE_B2(j, L)                                                          \
  __builtin_amdgcn_global_load_lds(AS1(Bsrc + (L)*lstep + (j)*128),             \
      AS3(smem + 98304 + ((j)&1) * 16384 + (L)*8192 + t * 16), 16, 0, 0)

  const int xr = fr << 3;
  const char* ArdRow = smem + (wr * 64 + fr) * 128;
  const char* BrdRow = smem + 98304 + (wc * 64 + fr) * 128;
#define RD_A2(ar_, m, j) \
  (*(const long*)(ArdRow + (ar_)*32768 + (m)*2048 + ((fk * 32 + (j)*8) ^ xr)))
#define RD_B2(pb_, n, j) \
  (*(const long*)(BrdRow + (pb_)*16384 + (n)*2048 + ((fk * 32 + (j)*8) ^ xr)))

  f32x4 acc[4][4];
#pragma unroll
  for (int m = 0; m < 4; m++)
#pragma unroll
    for (int n = 0; n < 4; n++) acc[m][n] = (f32x4)0.f;

  STAGE_A2(0, 0, 0, 0); STAGE_A2(0, 0, 0, 1); STAGE_A2(0, 0, 1, 0); STAGE_A2(0, 0, 1, 1);
  STAGE_B2(0, 0); STAGE_B2(0, 1);
  STAGE_A2(1, 1, 0, 0); STAGE_A2(1, 1, 0, 1); STAGE_A2(1, 1, 1, 0); STAGE_A2(1, 1, 1, 1);
  STAGE_B2(1, 0); STAGE_B2(1, 1);
  asm volatile("s_waitcnt vmcnt(6)" ::: "memory");
  __builtin_amdgcn_s_barrier();

  l64x4 bfr[4];
  l64x4 ap[2];
#pragma unroll
  for (int j = 0; j < 4; ++j) ap[0][j] = RD_A2(0, 0, j);

  int ar = 0;
  for (int g = 0; g < NT; ++g) {
    const int pb = g & 1;
    int sr = ar + 2; if (sr >= 3) sr -= 3;
    int nar = ar + 1; if (nar >= 3) nar = 0;
    const bool st = (g + 2 < NT);
#pragma unroll
    for (int p = 0; p < 4; ++p) {
      const int cs = p & 1, ns = cs ^ 1;
      if (p == 0) {
#pragma unroll
        for (int n = 0; n < 4; ++n)
#pragma unroll
          for (int j = 0; j < 4; ++j) bfr[n][j] = RD_B2(pb, n, j);
      }
      asm volatile("s_waitcnt lgkmcnt(0)" ::: "memory");
      __builtin_amdgcn_sched_barrier(0);
      __builtin_amdgcn_s_setprio(1);
#pragma unroll
      for (int n = 0; n < 4; ++n) {
        MFMA_SC(acc[p][n], ap[cs], bfr[n])
      }
      __builtin_amdgcn_s_setprio(0);
      if (p < 3) {
#pragma unroll
        for (int j = 0; j < 4; ++j) ap[ns][j] = RD_A2(ar, p + 1, j);
      } else if (g + 1 < NT) {
#pragma unroll
        for (int j = 0; j < 4; ++j) ap[ns][j] = RD_A2(nar, 0, j);
      }
      if (st) {
        if (p == 0) { STAGE_A2(g + 2, sr, 0, 0); STAGE_A2(g + 2, sr, 0, 1); }
        if (p == 1) { STAGE_A2(g + 2, sr, 1, 0); STAGE_A2(g + 2, sr, 1, 1); }
        if (p == 2) { STAGE_B2(g + 2, 0); STAGE_B2(g + 2, 1); }
      }
      if (p == 2 && g + 1 < NT) {
        if (st) asm volatile("s_waitcnt vmcnt(6)" ::: "memory");
        else    asm volatile("s_waitcnt vmcnt(0)" ::: "memory");
      }
      asm volatile("s_barrier" ::: "memory");
    }
    ar = nar;
  }

  // ---- row stats (LDS dead after final barrier) ----
  float* stats = (float*)smem;
  if (t < 256) {
    float s = 0.f, q = 0.f;
#pragma unroll
    for (int tb = 0; tb < 16; ++tb) {
      const float* p = pp + (((long)(tm * 16 + tb) * 256 + t) * 2);
      s += p[0];
      q += p[1];
    }
    float mu = s * (1.f / 4096.f);
    float var = q * (1.f / 4096.f) - mu * mu;
    stats[t * 2] = mu;
    stats[t * 2 + 1] = rsqrtf(var + 1e-6f);
  }
  __syncthreads();

  float bi[4], ga[4], wl[4], bl[4];
#pragma unroll
  for (int n = 0; n < 4; ++n) {
    const long col = bcol + wc * 64 + n * 16 + fr;
    bi[n] = bias[col];
    ga[n] = gamma[col];
    wl[n] = w2l[col];
    bl[n] = b2l[col];
  }
  const long orow = brow + wr * 64 + fk * 4;
  const long ocol = bcol + wc * 64 + fr;
  const int rl0 = wr * 64 + fk * 4;
#pragma unroll
  for (int m = 0; m < 4; ++m)
#pragma unroll
    for (int r = 0; r < 4; ++r) {
      const long row = orow + m * 16 + r;
      const int rl = rl0 + m * 16 + r;
      const float mu = stats[rl * 2];
      const float rs = stats[rl * 2 + 1];
#pragma unroll
      for (int n = 0; n < 4; ++n) {
        const long col = ocol + n * 16;
        float v = rs * (acc[m][n][r] * 0.03125f) - rs * mu * wl[n] + bl[n] + bi[n];
        Cf[row * (long)N + col] = v * ga[n] + resid[row * (long)N + col];
      }
    }
#undef STAGE_A2
#undef STAGE_B2
#undef RD_A2
#undef RD_B2
}

extern "C" void kernel_launch(void* const* d_in, const int* in_sizes, int n_in,
                              void* d_out, int out_size, void* d_ws, size_t ws_size,
                              hipStream_t stream) {
  const float* x     = (const float*)d_in[0];
  const float* W1    = (const float*)d_in[1];
  const float* b1    = (const float*)d_in[2];
  const float* ln_w  = (const float*)d_in[3];
  const float* ln_b  = (const float*)d_in[4];
  const float* W2    = (const float*)d_in[5];
  const float* b2    = (const float*)d_in[6];
  const float* gamma = (const float*)d_in[7];
  float* out = (float*)d_out;

  const int Nr = 8192, DIM = 1024, DFF = 4096, K1 = 3072;

  unsigned char* W1q   = (unsigned char*)d_ws;
  unsigned char* W2q   = W1q + (long)DFF * K1;
  unsigned char* h_in  = W2q + (long)DIM * DFF;
  unsigned char* h_act = h_in + (long)Nr * K1;
  float* partial = (float*)(h_act + (long)Nr * DFF);
  float* pp      = partial + 128 * 1024;
  float* w2l     = pp + 32 * 16 * 256 * 2;
  float* b2l     = w2l + DIM;

  hipFuncSetAttribute((const void*)gemm256_relu,
                      hipFuncAttributeMaxDynamicSharedMemorySize, 163840);
  hipFuncSetAttribute((const void*)gemm256_g2,
                      hipFuncAttributeMaxDynamicSharedMemorySize, 131072);

  prep<<<3584, 256, 0, stream>>>(W1, W1q, W2, W2q, x, partial, ln_w, ln_b, w2l, b2l);

  scan_emit<<<dim3(4, 128), 256, 0, stream>>>(x, partial, h_in);

  // GEMM1 (MX-fp8 16x16x128): h' = relu(h_in @ W1q^T / 32 + b1)*lnw -> fp8, + LN stats
  gemm256_relu<<<512, 512, 163840, stream>>>(h_in, W1q, h_act, b1, ln_w, pp,
                                             Nr, DFF, K1);

  // GEMM2 (MX-fp8 16x16x128, stats fused): out = (...)*gamma + x
  gemm256_g2<<<256, 512, 131072, stream>>>(h_act, W2q, out, b2, gamma, x,
                                           w2l, b2l, pp, Nr, DIM, DFF);
}

// Round 19
// 283.189 us; speedup vs baseline: 1.2676x; 1.2676x over previous
//
#include <hip/hip_runtime.h>

typedef __attribute__((ext_vector_type(4))) float f32x4;

#define AS1(p) ((const __attribute__((address_space(1))) void*)(p))
#define AS3(p) ((__attribute__((address_space(3))) void*)(p))

__device__ __forceinline__ unsigned short f2bf(float f) {
  unsigned u = __builtin_bit_cast(unsigned, f);
  u += 0x7fffu + ((u >> 16) & 1u);
  return (unsigned short)(u >> 16);
}
// fp32 -> OCP e4m3fn (RNE, FTZ below 2^-6, clamp 448)
__device__ __forceinline__ unsigned f2e4m3(float f) {
  unsigned uf = __builtin_bit_cast(unsigned, f);
  unsigned s = (uf >> 24) & 0x80u;
  unsigned u = uf & 0x7fffffffu;
  if (u < 0x3c800000u) return s;
  if (u > 0x43e00000u) u = 0x43e00000u;
  u += 0x7ffffu + ((u >> 20) & 1u);
  unsigned v = (u >> 20) - 960u;
  if (v > 126u) v = 126u;
  return s | v;
}

// Global pre-swizzle rule for fp8 GEMM operands (verified r15: conflicts 1.9e7->98K):
//   phys_k = (k & ~127) | ((k & 127) ^ ((row & 15) << 3))
// r18 ERRATA: MX-scaled 16x16x128 MFMA REJECTED on this schedule — v8i32 operand
// tuples (6 live x 8 VGPR) + 128 AGPR acc spill to scratch (WRITE_SIZE 33.8->382MB,
// MfmaUtil 51->17%). Non-scaled fp8 16x16x32 is the right operating point here.

// ---------------- fused prep: W1/W2 fp8 casts + chunkmax + w2_fold ----------------
__global__ __launch_bounds__(256) void prep(const float* __restrict__ W1,
                                            unsigned char* __restrict__ W1q,
                                            const float* __restrict__ W2,
                                            unsigned char* __restrict__ W2q,
                                            const float* __restrict__ x,
                                            float* __restrict__ partial,
                                            const float* __restrict__ lnw,
                                            const float* __restrict__ lnb,
                                            float* __restrict__ w2l,
                                            float* __restrict__ b2l) {
  __shared__ float ss[4], bb[4];
  const int bid = blockIdx.x;
  if (bid < 1536) {
    long i = ((long)bid * 256 + threadIdx.x) * 4;
    const long n1 = (long)4096 * 3072;
    const long stride = (long)1536 * 256 * 4;
    for (; i < n1; i += stride) {
      float4 f = *(const float4*)(W1 + i);
      unsigned v = f2e4m3(f.x * 32.f) | (f2e4m3(f.y * 32.f) << 8) |
                   (f2e4m3(f.z * 32.f) << 16) | (f2e4m3(f.w * 32.f) << 24);
      long n = i / 3072;
      long k = i - n * 3072;
      long phys = n * 3072 + (k & ~(long)127) + ((k & 127) ^ ((n & 15) << 3));
      *(unsigned*)(W1q + phys) = v;
    }
  } else if (bid < 2048) {
    long i = ((long)(bid - 1536) * 256 + threadIdx.x) * 4;
    const long n2 = (long)1024 * 4096;
    const long stride = (long)512 * 256 * 4;
    for (; i < n2; i += stride) {
      float4 f = *(const float4*)(W2 + i);
      unsigned v = f2e4m3(f.x * 32.f) | (f2e4m3(f.y * 32.f) << 8) |
                   (f2e4m3(f.z * 32.f) << 16) | (f2e4m3(f.w * 32.f) << 24);
      long n = i >> 12;
      long k = i & 4095;
      long phys = (n << 12) + (k & ~(long)127) + ((k & 127) ^ ((n & 15) << 3));
      *(unsigned*)(W2q + phys) = v;
    }
  } else if (bid < 2560) {
    const int b = bid - 2048;
    const int col = (b & 3) * 256 + threadIdx.x;
    const int chunk = b >> 2;
    const float* p = x + (long)chunk * 64 * 1024 + col;
    float m = -INFINITY;
#pragma unroll 4
    for (int i = 0; i < 64; i++) m = fmaxf(m, p[(long)i * 1024]);
    partial[chunk * 1024 + col] = m;
  } else {
    const int n = bid - 2560;
    const float* w = W2 + (long)n * 4096;
    float s = 0.f, b = 0.f;
    for (int k = threadIdx.x; k < 4096; k += 256) {
      float wv = w[k];
      s += wv * lnw[k];
      b += wv * lnb[k];
    }
#pragma unroll
    for (int off = 32; off; off >>= 1) {
      s += __shfl_xor(s, off, 64);
      b += __shfl_xor(b, off, 64);
    }
    const int wv2 = threadIdx.x >> 6;
    if ((threadIdx.x & 63) == 0) { ss[wv2] = s; bb[wv2] = b; }
    __syncthreads();
    if (threadIdx.x == 0) {
      w2l[n] = ss[0] + ss[1] + ss[2] + ss[3];
      b2l[n] = bb[0] + bb[1] + bb[2] + bb[3];
    }
  }
}

// ---------------- scan_emit with inline chunk-scan: h_in fp8 pre-swizzled ----------------
__global__ __launch_bounds__(256) void scan_emit(const float* __restrict__ x,
                                                 const float* __restrict__ partial,
                                                 unsigned char* __restrict__ h_in) {
  const int col = blockIdx.x * 256 + threadIdx.x;
  const int chunk = blockIdx.y;
  float pre = -INFINITY, suf = -INFINITY;
#pragma unroll
  for (int c = 0; c < 128; ++c) {
    float pv = partial[c * 1024 + col];
    if (c < chunk) pre = fmaxf(pre, pv);
    if (c > chunk) suf = fmaxf(suf, pv);
  }
  long r0 = (long)chunk * 64;
  const int cb = col & ~127, cw = col & 127;
  float run = pre;
  for (int i = 0; i < 64; i++) {
    long row = r0 + i;
    int xo = (int)(row & 15) << 3;
    int c0 = cb | (cw ^ xo);
    float v = x[row * 1024 + col];
    unsigned char* hr = h_in + row * 3072;
    hr[c0] = (unsigned char)f2e4m3(v);
    hr[1024 + c0] = (unsigned char)(row == 0 ? 0u : f2e4m3(run));
    run = fmaxf(run, v);
  }
  float run2 = suf;
  for (int i = 63; i >= 0; i--) {
    long row = r0 + i;
    int xo = (int)(row & 15) << 3;
    int c0 = cb | (cw ^ xo);
    float v = x[row * 1024 + col];
    h_in[row * 3072 + 2048 + c0] = (unsigned char)(row == 8191 ? 0u : f2e4m3(run2));
    run2 = fmaxf(run2, v);
  }
}

// ============ 256x256 FP8 GEMM1, BK=128 (r15/r16/r17 verified) ============
__global__ __launch_bounds__(512, 2) void gemm256_relu(
    const unsigned char* __restrict__ A, const unsigned char* __restrict__ B,
    unsigned char* __restrict__ C, const float* __restrict__ bias,
    const float* __restrict__ lnw, float* __restrict__ pp,
    int M, int N, int K) {
  extern __shared__ char smem[];
  const int NT = K >> 7;

  const int nwg = gridDim.x;
  const int cpx = nwg >> 3;
  const int bid = blockIdx.x;
  const int swz = (bid & 7) * cpx + (bid >> 3);
  const int tiles_m = M >> 8;
  const int tm = swz % tiles_m;
  const int tn = swz / tiles_m;
  const long brow = (long)tm * 256;
  const long bcol = (long)tn * 256;

  const int t = threadIdx.x;
  const int lane = t & 63, wv = t >> 6;
  const int wr = wv >> 2, wc = wv & 3;
  const int fr = lane & 15, fk = lane >> 4;

  const int srow = t >> 3;
  const int scol = (t & 7) * 16;
  const unsigned char* Asrc = A + (brow + srow) * (long)K + scol;
  const unsigned char* Bsrc = B + (bcol + srow) * (long)K + scol;
  const long hstep = (long)128 * K, lstep = (long)64 * K;

#define STAGE_A(j, reg, h, L)                                                   \
  __builtin_amdgcn_global_load_lds(AS1(Asrc + (h)*hstep + (L)*lstep + (j)*128), \
      AS3(smem + (reg)*32768 + (h)*16384 + (L)*8192 + t * 16), 16, 0, 0)
#define STAGE_B(j, h, L)                                                        \
  __builtin_amdgcn_global_load_lds(AS1(Bsrc + (h)*hstep + (L)*lstep + (j)*128), \
      AS3(smem + 98304 + ((j)&1) * 32768 + (h)*16384 + (L)*8192 + t * 16), 16, 0, 0)

  const int xr = fr << 3;
  const char* ArdRow = smem + (wr * 128 + fr) * 128;
  const char* BrdRow = smem + 98304 + (wc * 64 + fr) * 128;
#define RD_A(ar_, m, kk) \
  (*(const long*)(ArdRow + (ar_)*32768 + (m)*2048 + (((kk)*32 + fk * 8) ^ xr)))
#define RD_B(pb_, n, kk) \
  (*(const long*)(BrdRow + (pb_)*32768 + (n)*2048 + (((kk)*32 + fk * 8) ^ xr)))

#define MFMA_QUAD(mi, a_)                                                      \
  _Pragma("unroll")                                                            \
  for (int n = 0; n < 4; ++n) {                                                \
    _Pragma("unroll")                                                          \
    for (int kk = 0; kk < 4; ++kk)                                             \
      acc[(mi)][n] = __builtin_amdgcn_mfma_f32_16x16x32_fp8_fp8(               \
          a_[kk], bfr[n][kk], acc[(mi)][n], 0, 0, 0);                          \
  }

  f32x4 acc[8][4];
#pragma unroll
  for (int m = 0; m < 8; m++)
#pragma unroll
    for (int n = 0; n < 4; n++) acc[m][n] = (f32x4)0.f;

  STAGE_A(0, 0, 0, 0); STAGE_A(0, 0, 0, 1); STAGE_A(0, 0, 1, 0); STAGE_A(0, 0, 1, 1);
  STAGE_B(0, 0, 0); STAGE_B(0, 0, 1); STAGE_B(0, 1, 0); STAGE_B(0, 1, 1);
  STAGE_A(1, 1, 0, 0); STAGE_A(1, 1, 0, 1); STAGE_A(1, 1, 1, 0); STAGE_A(1, 1, 1, 1);
  STAGE_B(1, 0, 0); STAGE_B(1, 0, 1); STAGE_B(1, 1, 0); STAGE_B(1, 1, 1);
  asm volatile("s_waitcnt vmcnt(8)" ::: "memory");
  __builtin_amdgcn_s_barrier();

  long bfr[4][4];
  long ap[2][2][4];
  ap[0][0][0] = RD_A(0, 0, 0); ap[0][0][1] = RD_A(0, 0, 1);
  ap[0][0][2] = RD_A(0, 0, 2); ap[0][0][3] = RD_A(0, 0, 3);
  ap[0][1][0] = RD_A(0, 1, 0); ap[0][1][1] = RD_A(0, 1, 1);
  ap[0][1][2] = RD_A(0, 1, 2); ap[0][1][3] = RD_A(0, 1, 3);

  int ar = 0;
  for (int g = 0; g < NT; ++g) {
    const int pb = g & 1;
    int sr = ar + 2; if (sr >= 3) sr -= 3;
    int nar = ar + 1; if (nar >= 3) nar = 0;
    const bool st = (g + 2 < NT);
#pragma unroll
    for (int p = 0; p < 4; ++p) {
      const int cs = p & 1, ns = cs ^ 1;
      if (p == 0) {
#pragma unroll
        for (int n = 0; n < 4; ++n)
#pragma unroll
          for (int kk = 0; kk < 4; ++kk) bfr[n][kk] = RD_B(pb, n, kk);
      }
      asm volatile("s_waitcnt lgkmcnt(0)" ::: "memory");
      __builtin_amdgcn_sched_barrier(0);
      __builtin_amdgcn_s_setprio(1);
      MFMA_QUAD(2 * p, ap[cs][0])
      MFMA_QUAD(2 * p + 1, ap[cs][1])
      __builtin_amdgcn_s_setprio(0);
      if (p < 3) {
#pragma unroll
        for (int kk = 0; kk < 4; ++kk) {
          ap[ns][0][kk] = RD_A(ar, 2 * p + 2, kk);
          ap[ns][1][kk] = RD_A(ar, 2 * p + 3, kk);
        }
      } else if (g + 1 < NT) {
#pragma unroll
        for (int kk = 0; kk < 4; ++kk) {
          ap[ns][0][kk] = RD_A(nar, 0, kk);
          ap[ns][1][kk] = RD_A(nar, 1, kk);
        }
      }
      if (st) {
        if (p == 0) { STAGE_A(g + 2, sr, 0, 0); STAGE_A(g + 2, sr, 0, 1); }
        if (p == 1) { STAGE_A(g + 2, sr, 1, 0); STAGE_A(g + 2, sr, 1, 1); }
        if (p == 2) { STAGE_B(g + 2, 0, 0); STAGE_B(g + 2, 0, 1); }
        if (p == 3) { STAGE_B(g + 2, 1, 0); STAGE_B(g + 2, 1, 1); }
      }
      if (p == 2 && g + 1 < NT) {
        if (st) asm volatile("s_waitcnt vmcnt(6)" ::: "memory");
        else    asm volatile("s_waitcnt vmcnt(0)" ::: "memory");
      }
      asm volatile("s_barrier" ::: "memory");
    }
    ar = nar;
  }

  float bi[4], lw[4];
#pragma unroll
  for (int n = 0; n < 4; ++n) {
    const long col = bcol + wc * 64 + n * 16 + fr;
    bi[n] = bias[col];
    lw[n] = lnw[col];
  }
  float* sred = (float*)smem;
  float* qred = sred + 1024;
  const long orow = brow + wr * 128 + fk * 4;
  const int ocol = (int)bcol + wc * 64 + fr;
#pragma unroll
  for (int m = 0; m < 8; ++m) {
#pragma unroll
    for (int r = 0; r < 4; ++r) {
      const long row = orow + m * 16 + r;
      const int xo = ((fk * 4 + r) & 15) << 3;
      float s = 0.f, q = 0.f;
#pragma unroll
      for (int n = 0; n < 4; ++n) {
        float v = acc[m][n][r] * 0.03125f + bi[n];
        v = v > 0.f ? v : 0.f;
        s += v;
        q += v * v;
        const int col = ocol + n * 16;
        const int phys = (col & ~127) | ((col & 127) ^ xo);
        C[row * (long)N + phys] = (unsigned char)f2e4m3(v * lw[n]);
      }
#pragma unroll
      for (int off = 1; off < 16; off <<= 1) {
        s += __shfl_xor(s, off, 64);
        q += __shfl_xor(q, off, 64);
      }
      if (fr == 0) {
        int rl = wr * 128 + m * 16 + fk * 4 + r;
        sred[rl * 4 + wc] = s;
        qred[rl * 4 + wc] = q;
      }
    }
  }
  __syncthreads();
  if (t < 256) {
    float s = sred[t * 4] + sred[t * 4 + 1] + sred[t * 4 + 2] + sred[t * 4 + 3];
    float q = qred[t * 4] + qred[t * 4 + 1] + qred[t * 4 + 2] + qred[t * 4 + 3];
    float* pb = pp + (((long)(tm * 16 + tn) * 256 + t) * 2);
    pb[0] = s;
    pb[1] = q;
  }
#undef STAGE_A
#undef STAGE_B
#undef RD_A
#undef RD_B
#undef MFMA_QUAD
}

// ============ 256x128 FP8 GEMM2, BK=128 (r16 main loop; r17 stats fused) ============
__global__ __launch_bounds__(512, 2) void gemm256_g2(
    const unsigned char* __restrict__ A, const unsigned char* __restrict__ B,
    float* __restrict__ Cf, const float* __restrict__ bias,
    const float* __restrict__ gamma, const float* __restrict__ resid,
    const float* __restrict__ w2l, const float* __restrict__ b2l,
    const float* __restrict__ pp,
    int M, int N, int K) {
  extern __shared__ char smem[];
  const int NT = K >> 7;

  const int nwg = gridDim.x;
  const int cpx = nwg >> 3;
  const int bid = blockIdx.x;
  const int swz = (bid & 7) * cpx + (bid >> 3);
  const int tiles_m = M >> 8;
  const int tm = swz % tiles_m;
  const int tn = swz / tiles_m;
  const long brow = (long)tm * 256;
  const long bcol = (long)tn * 128;

  const int t = threadIdx.x;
  const int lane = t & 63, wv = t >> 6;
  const int wr = wv >> 1, wc = wv & 1;
  const int fr = lane & 15, fk = lane >> 4;

  const int srow = t >> 3;
  const int scol = (t & 7) * 16;
  const unsigned char* Asrc = A + (brow + srow) * (long)K + scol;
  const unsigned char* Bsrc = B + (bcol + srow) * (long)K + scol;
  const long hstep = (long)128 * K, lstep = (long)64 * K;

#define STAGE_A2(j, reg, h, L)                                                  \
  __builtin_amdgcn_global_load_lds(AS1(Asrc + (h)*hstep + (L)*lstep + (j)*128), \
      AS3(smem + (reg)*32768 + (h)*16384 + (L)*8192 + t * 16), 16, 0, 0)
#define STAGE_B2(j, L)                                                          \
  __builtin_amdgcn_global_load_lds(AS1(Bsrc + (L)*lstep + (j)*128),             \
      AS3(smem + 98304 + ((j)&1) * 16384 + (L)*8192 + t * 16), 16, 0, 0)

  const int xr = fr << 3;
  const char* ArdRow = smem + (wr * 64 + fr) * 128;
  const char* BrdRow = smem + 98304 + (wc * 64 + fr) * 128;
#define RD_A2(ar_, m, kk) \
  (*(const long*)(ArdRow + (ar_)*32768 + (m)*2048 + (((kk)*32 + fk * 8) ^ xr)))
#define RD_B2(pb_, n, kk) \
  (*(const long*)(BrdRow + (pb_)*16384 + (n)*2048 + (((kk)*32 + fk * 8) ^ xr)))

  f32x4 acc[4][4];
#pragma unroll
  for (int m = 0; m < 4; m++)
#pragma unroll
    for (int n = 0; n < 4; n++) acc[m][n] = (f32x4)0.f;

  STAGE_A2(0, 0, 0, 0); STAGE_A2(0, 0, 0, 1); STAGE_A2(0, 0, 1, 0); STAGE_A2(0, 0, 1, 1);
  STAGE_B2(0, 0); STAGE_B2(0, 1);
  STAGE_A2(1, 1, 0, 0); STAGE_A2(1, 1, 0, 1); STAGE_A2(1, 1, 1, 0); STAGE_A2(1, 1, 1, 1);
  STAGE_B2(1, 0); STAGE_B2(1, 1);
  asm volatile("s_waitcnt vmcnt(6)" ::: "memory");
  __builtin_amdgcn_s_barrier();

  long bfr[4][4];
  long ap[2][4];
  ap[0][0] = RD_A2(0, 0, 0); ap[0][1] = RD_A2(0, 0, 1);
  ap[0][2] = RD_A2(0, 0, 2); ap[0][3] = RD_A2(0, 0, 3);

  int ar = 0;
  for (int g = 0; g < NT; ++g) {
    const int pb = g & 1;
    int sr = ar + 2; if (sr >= 3) sr -= 3;
    int nar = ar + 1; if (nar >= 3) nar = 0;
    const bool st = (g + 2 < NT);
#pragma unroll
    for (int p = 0; p < 4; ++p) {
      const int cs = p & 1, ns = cs ^ 1;
      if (p == 0) {
#pragma unroll
        for (int n = 0; n < 4; ++n)
#pragma unroll
          for (int kk = 0; kk < 4; ++kk) bfr[n][kk] = RD_B2(pb, n, kk);
      }
      asm volatile("s_waitcnt lgkmcnt(0)" ::: "memory");
      __builtin_amdgcn_sched_barrier(0);
      __builtin_amdgcn_s_setprio(1);
#pragma unroll
      for (int n = 0; n < 4; ++n)
#pragma unroll
        for (int kk = 0; kk < 4; ++kk)
          acc[p][n] = __builtin_amdgcn_mfma_f32_16x16x32_fp8_fp8(
              ap[cs][kk], bfr[n][kk], acc[p][n], 0, 0, 0);
      __builtin_amdgcn_s_setprio(0);
      if (p < 3) {
#pragma unroll
        for (int kk = 0; kk < 4; ++kk) ap[ns][kk] = RD_A2(ar, p + 1, kk);
      } else if (g + 1 < NT) {
#pragma unroll
        for (int kk = 0; kk < 4; ++kk) ap[ns][kk] = RD_A2(nar, 0, kk);
      }
      if (st) {
        if (p == 0) { STAGE_A2(g + 2, sr, 0, 0); STAGE_A2(g + 2, sr, 0, 1); }
        if (p == 1) { STAGE_A2(g + 2, sr, 1, 0); STAGE_A2(g + 2, sr, 1, 1); }
        if (p == 2) { STAGE_B2(g + 2, 0); STAGE_B2(g + 2, 1); }
      }
      if (p == 2 && g + 1 < NT) {
        if (st) asm volatile("s_waitcnt vmcnt(6)" ::: "memory");
        else    asm volatile("s_waitcnt vmcnt(0)" ::: "memory");
      }
      asm volatile("s_barrier" ::: "memory");
    }
    ar = nar;
  }

  // ---- row stats (LDS dead after final barrier) ----
  float* stats = (float*)smem;
  if (t < 256) {
    float s = 0.f, q = 0.f;
#pragma unroll
    for (int tb = 0; tb < 16; ++tb) {
      const float* p = pp + (((long)(tm * 16 + tb) * 256 + t) * 2);
      s += p[0];
      q += p[1];
    }
    float mu = s * (1.f / 4096.f);
    float var = q * (1.f / 4096.f) - mu * mu;
    stats[t * 2] = mu;
    stats[t * 2 + 1] = rsqrtf(var + 1e-6f);
  }
  __syncthreads();

  float bi[4], ga[4], wl[4], bl[4];
#pragma unroll
  for (int n = 0; n < 4; ++n) {
    const long col = bcol + wc * 64 + n * 16 + fr;
    bi[n] = bias[col];
    ga[n] = gamma[col];
    wl[n] = w2l[col];
    bl[n] = b2l[col];
  }
  const long orow = brow + wr * 64 + fk * 4;
  const long ocol = bcol + wc * 64 + fr;
  const int rl0 = wr * 64 + fk * 4;
#pragma unroll
  for (int m = 0; m < 4; ++m)
#pragma unroll
    for (int r = 0; r < 4; ++r) {
      const long row = orow + m * 16 + r;
      const int rl = rl0 + m * 16 + r;
      const float mu = stats[rl * 2];
      const float rs = stats[rl * 2 + 1];
#pragma unroll
      for (int n = 0; n < 4; ++n) {
        const long col = ocol + n * 16;
        float v = rs * (acc[m][n][r] * 0.03125f) - rs * mu * wl[n] + bl[n] + bi[n];
        Cf[row * (long)N + col] = v * ga[n] + resid[row * (long)N + col];
      }
    }
#undef STAGE_A2
#undef STAGE_B2
#undef RD_A2
#undef RD_B2
}

extern "C" void kernel_launch(void* const* d_in, const int* in_sizes, int n_in,
                              void* d_out, int out_size, void* d_ws, size_t ws_size,
                              hipStream_t stream) {
  const float* x     = (const float*)d_in[0];
  const float* W1    = (const float*)d_in[1];
  const float* b1    = (const float*)d_in[2];
  const float* ln_w  = (const float*)d_in[3];
  const float* ln_b  = (const float*)d_in[4];
  const float* W2    = (const float*)d_in[5];
  const float* b2    = (const float*)d_in[6];
  const float* gamma = (const float*)d_in[7];
  float* out = (float*)d_out;

  const int Nr = 8192, DIM = 1024, DFF = 4096, K1 = 3072;

  unsigned char* W1q   = (unsigned char*)d_ws;
  unsigned char* W2q   = W1q + (long)DFF * K1;
  unsigned char* h_in  = W2q + (long)DIM * DFF;
  unsigned char* h_act = h_in + (long)Nr * K1;
  float* partial = (float*)(h_act + (long)Nr * DFF);
  float* pp      = partial + 128 * 1024;
  float* w2l     = pp + 32 * 16 * 256 * 2;
  float* b2l     = w2l + DIM;

  hipFuncSetAttribute((const void*)gemm256_relu,
                      hipFuncAttributeMaxDynamicSharedMemorySize, 163840);
  hipFuncSetAttribute((const void*)gemm256_g2,
                      hipFuncAttributeMaxDynamicSharedMemorySize, 131072);

  prep<<<3584, 256, 0, stream>>>(W1, W1q, W2, W2q, x, partial, ln_w, ln_b, w2l, b2l);

  scan_emit<<<dim3(4, 128), 256, 0, stream>>>(x, partial, h_in);

  // GEMM1 (fp8 BK=128): h' = relu(h_in @ W1q^T / 32 + b1)*lnw -> fp8, + LN stats
  gemm256_relu<<<512, 512, 163840, stream>>>(h_in, W1q, h_act, b1, ln_w, pp,
                                             Nr, DFF, K1);

  // GEMM2 (fp8 BK=128, stats fused): out = (...)*gamma + x
  gemm256_g2<<<256, 512, 131072, stream>>>(h_act, W2q, out, b2, gamma, x,
                                           w2l, b2l, pp, Nr, DIM, DFF);
}

// Round 20
// 278.238 us; speedup vs baseline: 1.2902x; 1.0178x over previous
//
#include <hip/hip_runtime.h>

typedef __attribute__((ext_vector_type(4))) float f32x4;

#define AS1(p) ((const __attribute__((address_space(1))) void*)(p))
#define AS3(p) ((__attribute__((address_space(3))) void*)(p))

__device__ __forceinline__ unsigned short f2bf(float f) {
  unsigned u = __builtin_bit_cast(unsigned, f);
  u += 0x7fffu + ((u >> 16) & 1u);
  return (unsigned short)(u >> 16);
}
// fp32 -> OCP e4m3fn (RNE, FTZ below 2^-6, clamp 448)
__device__ __forceinline__ unsigned f2e4m3(float f) {
  unsigned uf = __builtin_bit_cast(unsigned, f);
  unsigned s = (uf >> 24) & 0x80u;
  unsigned u = uf & 0x7fffffffu;
  if (u < 0x3c800000u) return s;
  if (u > 0x43e00000u) u = 0x43e00000u;
  u += 0x7ffffu + ((u >> 20) & 1u);
  unsigned v = (u >> 20) - 960u;
  if (v > 126u) v = 126u;
  return s | v;
}

// Global pre-swizzle rule for fp8 GEMM operands (verified r15: conflicts 1.9e7->98K):
//   phys_k = (k & ~127) | ((k & 127) ^ ((row & 15) << 3))
// r20: B-read moved to p3 of the PREVIOUS tile (one-phase lead, like r8's A).
// Basis: vmcnt(6)+barrier at p2 publishes ALL of tile g+1 — the same wait that
// already legitimizes the p3 A-read-ahead. Register-neutral (bfr refilled in
// place after its last use). B region pb^1 is re-staged only at tile g+1 p2,
// two barriers after every wave's p0 lgkmcnt(0) retires these reads.

// ---------------- fused prep: W1/W2 fp8 casts + chunkmax + w2_fold ----------------
__global__ __launch_bounds__(256) void prep(const float* __restrict__ W1,
                                            unsigned char* __restrict__ W1q,
                                            const float* __restrict__ W2,
                                            unsigned char* __restrict__ W2q,
                                            const float* __restrict__ x,
                                            float* __restrict__ partial,
                                            const float* __restrict__ lnw,
                                            const float* __restrict__ lnb,
                                            float* __restrict__ w2l,
                                            float* __restrict__ b2l) {
  __shared__ float ss[4], bb[4];
  const int bid = blockIdx.x;
  if (bid < 1536) {
    long i = ((long)bid * 256 + threadIdx.x) * 4;
    const long n1 = (long)4096 * 3072;
    const long stride = (long)1536 * 256 * 4;
    for (; i < n1; i += stride) {
      float4 f = *(const float4*)(W1 + i);
      unsigned v = f2e4m3(f.x * 32.f) | (f2e4m3(f.y * 32.f) << 8) |
                   (f2e4m3(f.z * 32.f) << 16) | (f2e4m3(f.w * 32.f) << 24);
      long n = i / 3072;
      long k = i - n * 3072;
      long phys = n * 3072 + (k & ~(long)127) + ((k & 127) ^ ((n & 15) << 3));
      *(unsigned*)(W1q + phys) = v;
    }
  } else if (bid < 2048) {
    long i = ((long)(bid - 1536) * 256 + threadIdx.x) * 4;
    const long n2 = (long)1024 * 4096;
    const long stride = (long)512 * 256 * 4;
    for (; i < n2; i += stride) {
      float4 f = *(const float4*)(W2 + i);
      unsigned v = f2e4m3(f.x * 32.f) | (f2e4m3(f.y * 32.f) << 8) |
                   (f2e4m3(f.z * 32.f) << 16) | (f2e4m3(f.w * 32.f) << 24);
      long n = i >> 12;
      long k = i & 4095;
      long phys = (n << 12) + (k & ~(long)127) + ((k & 127) ^ ((n & 15) << 3));
      *(unsigned*)(W2q + phys) = v;
    }
  } else if (bid < 2560) {
    const int b = bid - 2048;
    const int col = (b & 3) * 256 + threadIdx.x;
    const int chunk = b >> 2;
    const float* p = x + (long)chunk * 64 * 1024 + col;
    float m = -INFINITY;
#pragma unroll 4
    for (int i = 0; i < 64; i++) m = fmaxf(m, p[(long)i * 1024]);
    partial[chunk * 1024 + col] = m;
  } else {
    const int n = bid - 2560;
    const float* w = W2 + (long)n * 4096;
    float s = 0.f, b = 0.f;
    for (int k = threadIdx.x; k < 4096; k += 256) {
      float wv = w[k];
      s += wv * lnw[k];
      b += wv * lnb[k];
    }
#pragma unroll
    for (int off = 32; off; off >>= 1) {
      s += __shfl_xor(s, off, 64);
      b += __shfl_xor(b, off, 64);
    }
    const int wv2 = threadIdx.x >> 6;
    if ((threadIdx.x & 63) == 0) { ss[wv2] = s; bb[wv2] = b; }
    __syncthreads();
    if (threadIdx.x == 0) {
      w2l[n] = ss[0] + ss[1] + ss[2] + ss[3];
      b2l[n] = bb[0] + bb[1] + bb[2] + bb[3];
    }
  }
}

// ---------------- scan_emit with inline chunk-scan: h_in fp8 pre-swizzled ----------------
__global__ __launch_bounds__(256) void scan_emit(const float* __restrict__ x,
                                                 const float* __restrict__ partial,
                                                 unsigned char* __restrict__ h_in) {
  const int col = blockIdx.x * 256 + threadIdx.x;
  const int chunk = blockIdx.y;
  float pre = -INFINITY, suf = -INFINITY;
#pragma unroll
  for (int c = 0; c < 128; ++c) {
    float pv = partial[c * 1024 + col];
    if (c < chunk) pre = fmaxf(pre, pv);
    if (c > chunk) suf = fmaxf(suf, pv);
  }
  long r0 = (long)chunk * 64;
  const int cb = col & ~127, cw = col & 127;
  float run = pre;
  for (int i = 0; i < 64; i++) {
    long row = r0 + i;
    int xo = (int)(row & 15) << 3;
    int c0 = cb | (cw ^ xo);
    float v = x[row * 1024 + col];
    unsigned char* hr = h_in + row * 3072;
    hr[c0] = (unsigned char)f2e4m3(v);
    hr[1024 + c0] = (unsigned char)(row == 0 ? 0u : f2e4m3(run));
    run = fmaxf(run, v);
  }
  float run2 = suf;
  for (int i = 63; i >= 0; i--) {
    long row = r0 + i;
    int xo = (int)(row & 15) << 3;
    int c0 = cb | (cw ^ xo);
    float v = x[row * 1024 + col];
    h_in[row * 3072 + 2048 + c0] = (unsigned char)(row == 8191 ? 0u : f2e4m3(run2));
    run2 = fmaxf(run2, v);
  }
}

// ============ 256x256 FP8 GEMM1, BK=128 (r20: B one-phase-ahead) ============
__global__ __launch_bounds__(512, 2) void gemm256_relu(
    const unsigned char* __restrict__ A, const unsigned char* __restrict__ B,
    unsigned char* __restrict__ C, const float* __restrict__ bias,
    const float* __restrict__ lnw, float* __restrict__ pp,
    int M, int N, int K) {
  extern __shared__ char smem[];
  const int NT = K >> 7;

  const int nwg = gridDim.x;
  const int cpx = nwg >> 3;
  const int bid = blockIdx.x;
  const int swz = (bid & 7) * cpx + (bid >> 3);
  const int tiles_m = M >> 8;
  const int tm = swz % tiles_m;
  const int tn = swz / tiles_m;
  const long brow = (long)tm * 256;
  const long bcol = (long)tn * 256;

  const int t = threadIdx.x;
  const int lane = t & 63, wv = t >> 6;
  const int wr = wv >> 2, wc = wv & 3;
  const int fr = lane & 15, fk = lane >> 4;

  const int srow = t >> 3;
  const int scol = (t & 7) * 16;
  const unsigned char* Asrc = A + (brow + srow) * (long)K + scol;
  const unsigned char* Bsrc = B + (bcol + srow) * (long)K + scol;
  const long hstep = (long)128 * K, lstep = (long)64 * K;

#define STAGE_A(j, reg, h, L)                                                   \
  __builtin_amdgcn_global_load_lds(AS1(Asrc + (h)*hstep + (L)*lstep + (j)*128), \
      AS3(smem + (reg)*32768 + (h)*16384 + (L)*8192 + t * 16), 16, 0, 0)
#define STAGE_B(j, h, L)                                                        \
  __builtin_amdgcn_global_load_lds(AS1(Bsrc + (h)*hstep + (L)*lstep + (j)*128), \
      AS3(smem + 98304 + ((j)&1) * 32768 + (h)*16384 + (L)*8192 + t * 16), 16, 0, 0)

  const int xr = fr << 3;
  const char* ArdRow = smem + (wr * 128 + fr) * 128;
  const char* BrdRow = smem + 98304 + (wc * 64 + fr) * 128;
#define RD_A(ar_, m, kk) \
  (*(const long*)(ArdRow + (ar_)*32768 + (m)*2048 + (((kk)*32 + fk * 8) ^ xr)))
#define RD_B(pb_, n, kk) \
  (*(const long*)(BrdRow + (pb_)*32768 + (n)*2048 + (((kk)*32 + fk * 8) ^ xr)))

#define MFMA_QUAD(mi, a_)                                                      \
  _Pragma("unroll")                                                            \
  for (int n = 0; n < 4; ++n) {                                                \
    _Pragma("unroll")                                                          \
    for (int kk = 0; kk < 4; ++kk)                                             \
      acc[(mi)][n] = __builtin_amdgcn_mfma_f32_16x16x32_fp8_fp8(               \
          a_[kk], bfr[n][kk], acc[(mi)][n], 0, 0, 0);                          \
  }

  f32x4 acc[8][4];
#pragma unroll
  for (int m = 0; m < 8; m++)
#pragma unroll
    for (int n = 0; n < 4; n++) acc[m][n] = (f32x4)0.f;

  STAGE_A(0, 0, 0, 0); STAGE_A(0, 0, 0, 1); STAGE_A(0, 0, 1, 0); STAGE_A(0, 0, 1, 1);
  STAGE_B(0, 0, 0); STAGE_B(0, 0, 1); STAGE_B(0, 1, 0); STAGE_B(0, 1, 1);
  STAGE_A(1, 1, 0, 0); STAGE_A(1, 1, 0, 1); STAGE_A(1, 1, 1, 0); STAGE_A(1, 1, 1, 1);
  STAGE_B(1, 0, 0); STAGE_B(1, 0, 1); STAGE_B(1, 1, 0); STAGE_B(1, 1, 1);
  asm volatile("s_waitcnt vmcnt(8)" ::: "memory");
  __builtin_amdgcn_s_barrier();

  long bfr[4][4];
  long ap[2][2][4];
  // prologue reads: tile0 A m0/m1 AND tile0 B (r20)
  ap[0][0][0] = RD_A(0, 0, 0); ap[0][0][1] = RD_A(0, 0, 1);
  ap[0][0][2] = RD_A(0, 0, 2); ap[0][0][3] = RD_A(0, 0, 3);
  ap[0][1][0] = RD_A(0, 1, 0); ap[0][1][1] = RD_A(0, 1, 1);
  ap[0][1][2] = RD_A(0, 1, 2); ap[0][1][3] = RD_A(0, 1, 3);
#pragma unroll
  for (int n = 0; n < 4; ++n)
#pragma unroll
    for (int kk = 0; kk < 4; ++kk) bfr[n][kk] = RD_B(0, n, kk);

  int ar = 0;
  for (int g = 0; g < NT; ++g) {
    const int pb = g & 1;
    int sr = ar + 2; if (sr >= 3) sr -= 3;
    int nar = ar + 1; if (nar >= 3) nar = 0;
    const bool st = (g + 2 < NT);
#pragma unroll
    for (int p = 0; p < 4; ++p) {
      const int cs = p & 1, ns = cs ^ 1;
      asm volatile("s_waitcnt lgkmcnt(0)" ::: "memory");
      __builtin_amdgcn_sched_barrier(0);
      __builtin_amdgcn_s_setprio(1);
      MFMA_QUAD(2 * p, ap[cs][0])
      MFMA_QUAD(2 * p + 1, ap[cs][1])
      __builtin_amdgcn_s_setprio(0);
      if (p < 3) {
#pragma unroll
        for (int kk = 0; kk < 4; ++kk) {
          ap[ns][0][kk] = RD_A(ar, 2 * p + 2, kk);
          ap[ns][1][kk] = RD_A(ar, 2 * p + 3, kk);
        }
      } else if (g + 1 < NT) {
#pragma unroll
        for (int kk = 0; kk < 4; ++kk) {
          ap[ns][0][kk] = RD_A(nar, 0, kk);
          ap[ns][1][kk] = RD_A(nar, 1, kk);
        }
        // r20: refill bfr with tile g+1's B (published by p2's vmcnt+barrier);
        // drains under this phase's barrier + next p0's lgkm wait.
#pragma unroll
        for (int n = 0; n < 4; ++n)
#pragma unroll
          for (int kk = 0; kk < 4; ++kk) bfr[n][kk] = RD_B(pb ^ 1, n, kk);
      }
      if (st) {
        if (p == 0) { STAGE_A(g + 2, sr, 0, 0); STAGE_A(g + 2, sr, 0, 1); }
        if (p == 1) { STAGE_A(g + 2, sr, 1, 0); STAGE_A(g + 2, sr, 1, 1); }
        if (p == 2) { STAGE_B(g + 2, 0, 0); STAGE_B(g + 2, 0, 1); }
        if (p == 3) { STAGE_B(g + 2, 1, 0); STAGE_B(g + 2, 1, 1); }
      }
      if (p == 2 && g + 1 < NT) {
        if (st) asm volatile("s_waitcnt vmcnt(6)" ::: "memory");
        else    asm volatile("s_waitcnt vmcnt(0)" ::: "memory");
      }
      asm volatile("s_barrier" ::: "memory");
    }
    ar = nar;
  }

  float bi[4], lw[4];
#pragma unroll
  for (int n = 0; n < 4; ++n) {
    const long col = bcol + wc * 64 + n * 16 + fr;
    bi[n] = bias[col];
    lw[n] = lnw[col];
  }
  float* sred = (float*)smem;
  float* qred = sred + 1024;
  const long orow = brow + wr * 128 + fk * 4;
  const int ocol = (int)bcol + wc * 64 + fr;
#pragma unroll
  for (int m = 0; m < 8; ++m) {
#pragma unroll
    for (int r = 0; r < 4; ++r) {
      const long row = orow + m * 16 + r;
      const int xo = ((fk * 4 + r) & 15) << 3;
      float s = 0.f, q = 0.f;
#pragma unroll
      for (int n = 0; n < 4; ++n) {
        float v = acc[m][n][r] * 0.03125f + bi[n];
        v = v > 0.f ? v : 0.f;
        s += v;
        q += v * v;
        const int col = ocol + n * 16;
        const int phys = (col & ~127) | ((col & 127) ^ xo);
        C[row * (long)N + phys] = (unsigned char)f2e4m3(v * lw[n]);
      }
#pragma unroll
      for (int off = 1; off < 16; off <<= 1) {
        s += __shfl_xor(s, off, 64);
        q += __shfl_xor(q, off, 64);
      }
      if (fr == 0) {
        int rl = wr * 128 + m * 16 + fk * 4 + r;
        sred[rl * 4 + wc] = s;
        qred[rl * 4 + wc] = q;
      }
    }
  }
  __syncthreads();
  if (t < 256) {
    float s = sred[t * 4] + sred[t * 4 + 1] + sred[t * 4 + 2] + sred[t * 4 + 3];
    float q = qred[t * 4] + qred[t * 4 + 1] + qred[t * 4 + 2] + qred[t * 4 + 3];
    float* pb = pp + (((long)(tm * 16 + tn) * 256 + t) * 2);
    pb[0] = s;
    pb[1] = q;
  }
#undef STAGE_A
#undef STAGE_B
#undef RD_A
#undef RD_B
#undef MFMA_QUAD
}

// ============ 256x128 FP8 GEMM2, BK=128 (r20: B one-phase-ahead; stats fused) ============
__global__ __launch_bounds__(512, 2) void gemm256_g2(
    const unsigned char* __restrict__ A, const unsigned char* __restrict__ B,
    float* __restrict__ Cf, const float* __restrict__ bias,
    const float* __restrict__ gamma, const float* __restrict__ resid,
    const float* __restrict__ w2l, const float* __restrict__ b2l,
    const float* __restrict__ pp,
    int M, int N, int K) {
  extern __shared__ char smem[];
  const int NT = K >> 7;

  const int nwg = gridDim.x;
  const int cpx = nwg >> 3;
  const int bid = blockIdx.x;
  const int swz = (bid & 7) * cpx + (bid >> 3);
  const int tiles_m = M >> 8;
  const int tm = swz % tiles_m;
  const int tn = swz / tiles_m;
  const long brow = (long)tm * 256;
  const long bcol = (long)tn * 128;

  const int t = threadIdx.x;
  const int lane = t & 63, wv = t >> 6;
  const int wr = wv >> 1, wc = wv & 1;
  const int fr = lane & 15, fk = lane >> 4;

  const int srow = t >> 3;
  const int scol = (t & 7) * 16;
  const unsigned char* Asrc = A + (brow + srow) * (long)K + scol;
  const unsigned char* Bsrc = B + (bcol + srow) * (long)K + scol;
  const long hstep = (long)128 * K, lstep = (long)64 * K;

#define STAGE_A2(j, reg, h, L)                                                  \
  __builtin_amdgcn_global_load_lds(AS1(Asrc + (h)*hstep + (L)*lstep + (j)*128), \
      AS3(smem + (reg)*32768 + (h)*16384 + (L)*8192 + t * 16), 16, 0, 0)
#define STAGE_B2(j, L)                                                          \
  __builtin_amdgcn_global_load_lds(AS1(Bsrc + (L)*lstep + (j)*128),             \
      AS3(smem + 98304 + ((j)&1) * 16384 + (L)*8192 + t * 16), 16, 0, 0)

  const int xr = fr << 3;
  const char* ArdRow = smem + (wr * 64 + fr) * 128;
  const char* BrdRow = smem + 98304 + (wc * 64 + fr) * 128;
#define RD_A2(ar_, m, kk) \
  (*(const long*)(ArdRow + (ar_)*32768 + (m)*2048 + (((kk)*32 + fk * 8) ^ xr)))
#define RD_B2(pb_, n, kk) \
  (*(const long*)(BrdRow + (pb_)*16384 + (n)*2048 + (((kk)*32 + fk * 8) ^ xr)))

  f32x4 acc[4][4];
#pragma unroll
  for (int m = 0; m < 4; m++)
#pragma unroll
    for (int n = 0; n < 4; n++) acc[m][n] = (f32x4)0.f;

  STAGE_A2(0, 0, 0, 0); STAGE_A2(0, 0, 0, 1); STAGE_A2(0, 0, 1, 0); STAGE_A2(0, 0, 1, 1);
  STAGE_B2(0, 0); STAGE_B2(0, 1);
  STAGE_A2(1, 1, 0, 0); STAGE_A2(1, 1, 0, 1); STAGE_A2(1, 1, 1, 0); STAGE_A2(1, 1, 1, 1);
  STAGE_B2(1, 0); STAGE_B2(1, 1);
  asm volatile("s_waitcnt vmcnt(6)" ::: "memory");
  __builtin_amdgcn_s_barrier();

  long bfr[4][4];
  long ap[2][4];
  ap[0][0] = RD_A2(0, 0, 0); ap[0][1] = RD_A2(0, 0, 1);
  ap[0][2] = RD_A2(0, 0, 2); ap[0][3] = RD_A2(0, 0, 3);
#pragma unroll
  for (int n = 0; n < 4; ++n)
#pragma unroll
    for (int kk = 0; kk < 4; ++kk) bfr[n][kk] = RD_B2(0, n, kk);

  int ar = 0;
  for (int g = 0; g < NT; ++g) {
    const int pb = g & 1;
    int sr = ar + 2; if (sr >= 3) sr -= 3;
    int nar = ar + 1; if (nar >= 3) nar = 0;
    const bool st = (g + 2 < NT);
#pragma unroll
    for (int p = 0; p < 4; ++p) {
      const int cs = p & 1, ns = cs ^ 1;
      asm volatile("s_waitcnt lgkmcnt(0)" ::: "memory");
      __builtin_amdgcn_sched_barrier(0);
      __builtin_amdgcn_s_setprio(1);
#pragma unroll
      for (int n = 0; n < 4; ++n)
#pragma unroll
        for (int kk = 0; kk < 4; ++kk)
          acc[p][n] = __builtin_amdgcn_mfma_f32_16x16x32_fp8_fp8(
              ap[cs][kk], bfr[n][kk], acc[p][n], 0, 0, 0);
      __builtin_amdgcn_s_setprio(0);
      if (p < 3) {
#pragma unroll
        for (int kk = 0; kk < 4; ++kk) ap[ns][kk] = RD_A2(ar, p + 1, kk);
      } else if (g + 1 < NT) {
#pragma unroll
        for (int kk = 0; kk < 4; ++kk) ap[ns][kk] = RD_A2(nar, 0, kk);
#pragma unroll
        for (int n = 0; n < 4; ++n)
#pragma unroll
          for (int kk = 0; kk < 4; ++kk) bfr[n][kk] = RD_B2(pb ^ 1, n, kk);
      }
      if (st) {
        if (p == 0) { STAGE_A2(g + 2, sr, 0, 0); STAGE_A2(g + 2, sr, 0, 1); }
        if (p == 1) { STAGE_A2(g + 2, sr, 1, 0); STAGE_A2(g + 2, sr, 1, 1); }
        if (p == 2) { STAGE_B2(g + 2, 0); STAGE_B2(g + 2, 1); }
      }
      if (p == 2 && g + 1 < NT) {
        if (st) asm volatile("s_waitcnt vmcnt(6)" ::: "memory");
        else    asm volatile("s_waitcnt vmcnt(0)" ::: "memory");
      }
      asm volatile("s_barrier" ::: "memory");
    }
    ar = nar;
  }

  // ---- row stats (LDS dead after final barrier) ----
  float* stats = (float*)smem;
  if (t < 256) {
    float s = 0.f, q = 0.f;
#pragma unroll
    for (int tb = 0; tb < 16; ++tb) {
      const float* p = pp + (((long)(tm * 16 + tb) * 256 + t) * 2);
      s += p[0];
      q += p[1];
    }
    float mu = s * (1.f / 4096.f);
    float var = q * (1.f / 4096.f) - mu * mu;
    stats[t * 2] = mu;
    stats[t * 2 + 1] = rsqrtf(var + 1e-6f);
  }
  __syncthreads();

  float bi[4], ga[4], wl[4], bl[4];
#pragma unroll
  for (int n = 0; n < 4; ++n) {
    const long col = bcol + wc * 64 + n * 16 + fr;
    bi[n] = bias[col];
    ga[n] = gamma[col];
    wl[n] = w2l[col];
    bl[n] = b2l[col];
  }
  const long orow = brow + wr * 64 + fk * 4;
  const long ocol = bcol + wc * 64 + fr;
  const int rl0 = wr * 64 + fk * 4;
#pragma unroll
  for (int m = 0; m < 4; ++m)
#pragma unroll
    for (int r = 0; r < 4; ++r) {
      const long row = orow + m * 16 + r;
      const int rl = rl0 + m * 16 + r;
      const float mu = stats[rl * 2];
      const float rs = stats[rl * 2 + 1];
#pragma unroll
      for (int n = 0; n < 4; ++n) {
        const long col = ocol + n * 16;
        float v = rs * (acc[m][n][r] * 0.03125f) - rs * mu * wl[n] + bl[n] + bi[n];
        Cf[row * (long)N + col] = v * ga[n] + resid[row * (long)N + col];
      }
    }
#undef STAGE_A2
#undef STAGE_B2
#undef RD_A2
#undef RD_B2
}

extern "C" void kernel_launch(void* const* d_in, const int* in_sizes, int n_in,
                              void* d_out, int out_size, void* d_ws, size_t ws_size,
                              hipStream_t stream) {
  const float* x     = (const float*)d_in[0];
  const float* W1    = (const float*)d_in[1];
  const float* b1    = (const float*)d_in[2];
  const float* ln_w  = (const float*)d_in[3];
  const float* ln_b  = (const float*)d_in[4];
  const float* W2    = (const float*)d_in[5];
  const float* b2    = (const float*)d_in[6];
  const float* gamma = (const float*)d_in[7];
  float* out = (float*)d_out;

  const int Nr = 8192, DIM = 1024, DFF = 4096, K1 = 3072;

  unsigned char* W1q   = (unsigned char*)d_ws;
  unsigned char* W2q   = W1q + (long)DFF * K1;
  unsigned char* h_in  = W2q + (long)DIM * DFF;
  unsigned char* h_act = h_in + (long)Nr * K1;
  float* partial = (float*)(h_act + (long)Nr * DFF);
  float* pp      = partial + 128 * 1024;
  float* w2l     = pp + 32 * 16 * 256 * 2;
  float* b2l     = w2l + DIM;

  hipFuncSetAttribute((const void*)gemm256_relu,
                      hipFuncAttributeMaxDynamicSharedMemorySize, 163840);
  hipFuncSetAttribute((const void*)gemm256_g2,
                      hipFuncAttributeMaxDynamicSharedMemorySize, 131072);

  prep<<<3584, 256, 0, stream>>>(W1, W1q, W2, W2q, x, partial, ln_w, ln_b, w2l, b2l);

  scan_emit<<<dim3(4, 128), 256, 0, stream>>>(x, partial, h_in);

  // GEMM1 (fp8 BK=128, A+B one-phase-ahead): h' -> fp8, + LN stat partials
  gemm256_relu<<<512, 512, 163840, stream>>>(h_in, W1q, h_act, b1, ln_w, pp,
                                             Nr, DFF, K1);

  // GEMM2 (fp8 BK=128, stats fused): out = (...)*gamma + x
  gemm256_g2<<<256, 512, 131072, stream>>>(h_act, W2q, out, b2, gamma, x,
                                           w2l, b2l, pp, Nr, DIM, DFF);
}

// Round 21
// 276.952 us; speedup vs baseline: 1.2962x; 1.0046x over previous
//
#include <hip/hip_runtime.h>

typedef __attribute__((ext_vector_type(4))) float f32x4;

#define AS1(p) ((const __attribute__((address_space(1))) void*)(p))
#define AS3(p) ((__attribute__((address_space(3))) void*)(p))

__device__ __forceinline__ unsigned short f2bf(float f) {
  unsigned u = __builtin_bit_cast(unsigned, f);
  u += 0x7fffu + ((u >> 16) & 1u);
  return (unsigned short)(u >> 16);
}
// fp32 -> OCP e4m3fn (RNE, FTZ below 2^-6, clamp 448)
__device__ __forceinline__ unsigned f2e4m3(float f) {
  unsigned uf = __builtin_bit_cast(unsigned, f);
  unsigned s = (uf >> 24) & 0x80u;
  unsigned u = uf & 0x7fffffffu;
  if (u < 0x3c800000u) return s;
  if (u > 0x43e00000u) u = 0x43e00000u;
  u += 0x7ffffu + ((u >> 20) & 1u);
  unsigned v = (u >> 20) - 960u;
  if (v > 126u) v = 126u;
  return s | v;
}

// Global pre-swizzle rule for fp8 GEMM operands (verified r15: conflicts 1.9e7->98K):
//   phys_k = (k & ~127) | ((k & 127) ^ ((row & 15) << 3))
// r21: p1's trailing barrier removed (both GEMMs). Hazard audit: p0-trailing
// orders B(g)-read retirement before p2's B(g+2) same-parity stage; p2-trailing
// (with vmcnt(6)) publishes tile g+1 for p3's A/B read-ahead; p3-trailing orders
// region-ar read retirement (last reads issue at p2) before tile g+1's p0 stage
// into ar. p1's barrier guarded nothing (its stages hit region sr, untouched
// until tile g+2); removing it permits inter-wave skew across p1/p2.

// ---------------- fused prep: W1/W2 fp8 casts + chunkmax + w2_fold ----------------
__global__ __launch_bounds__(256) void prep(const float* __restrict__ W1,
                                            unsigned char* __restrict__ W1q,
                                            const float* __restrict__ W2,
                                            unsigned char* __restrict__ W2q,
                                            const float* __restrict__ x,
                                            float* __restrict__ partial,
                                            const float* __restrict__ lnw,
                                            const float* __restrict__ lnb,
                                            float* __restrict__ w2l,
                                            float* __restrict__ b2l) {
  __shared__ float ss[4], bb[4];
  const int bid = blockIdx.x;
  if (bid < 1536) {
    long i = ((long)bid * 256 + threadIdx.x) * 4;
    const long n1 = (long)4096 * 3072;
    const long stride = (long)1536 * 256 * 4;
    for (; i < n1; i += stride) {
      float4 f = *(const float4*)(W1 + i);
      unsigned v = f2e4m3(f.x * 32.f) | (f2e4m3(f.y * 32.f) << 8) |
                   (f2e4m3(f.z * 32.f) << 16) | (f2e4m3(f.w * 32.f) << 24);
      long n = i / 3072;
      long k = i - n * 3072;
      long phys = n * 3072 + (k & ~(long)127) + ((k & 127) ^ ((n & 15) << 3));
      *(unsigned*)(W1q + phys) = v;
    }
  } else if (bid < 2048) {
    long i = ((long)(bid - 1536) * 256 + threadIdx.x) * 4;
    const long n2 = (long)1024 * 4096;
    const long stride = (long)512 * 256 * 4;
    for (; i < n2; i += stride) {
      float4 f = *(const float4*)(W2 + i);
      unsigned v = f2e4m3(f.x * 32.f) | (f2e4m3(f.y * 32.f) << 8) |
                   (f2e4m3(f.z * 32.f) << 16) | (f2e4m3(f.w * 32.f) << 24);
      long n = i >> 12;
      long k = i & 4095;
      long phys = (n << 12) + (k & ~(long)127) + ((k & 127) ^ ((n & 15) << 3));
      *(unsigned*)(W2q + phys) = v;
    }
  } else if (bid < 2560) {
    const int b = bid - 2048;
    const int col = (b & 3) * 256 + threadIdx.x;
    const int chunk = b >> 2;
    const float* p = x + (long)chunk * 64 * 1024 + col;
    float m = -INFINITY;
#pragma unroll 4
    for (int i = 0; i < 64; i++) m = fmaxf(m, p[(long)i * 1024]);
    partial[chunk * 1024 + col] = m;
  } else {
    const int n = bid - 2560;
    const float* w = W2 + (long)n * 4096;
    float s = 0.f, b = 0.f;
    for (int k = threadIdx.x; k < 4096; k += 256) {
      float wv = w[k];
      s += wv * lnw[k];
      b += wv * lnb[k];
    }
#pragma unroll
    for (int off = 32; off; off >>= 1) {
      s += __shfl_xor(s, off, 64);
      b += __shfl_xor(b, off, 64);
    }
    const int wv2 = threadIdx.x >> 6;
    if ((threadIdx.x & 63) == 0) { ss[wv2] = s; bb[wv2] = b; }
    __syncthreads();
    if (threadIdx.x == 0) {
      w2l[n] = ss[0] + ss[1] + ss[2] + ss[3];
      b2l[n] = bb[0] + bb[1] + bb[2] + bb[3];
    }
  }
}

// ---------------- scan_emit with inline chunk-scan: h_in fp8 pre-swizzled ----------------
__global__ __launch_bounds__(256) void scan_emit(const float* __restrict__ x,
                                                 const float* __restrict__ partial,
                                                 unsigned char* __restrict__ h_in) {
  const int col = blockIdx.x * 256 + threadIdx.x;
  const int chunk = blockIdx.y;
  float pre = -INFINITY, suf = -INFINITY;
#pragma unroll
  for (int c = 0; c < 128; ++c) {
    float pv = partial[c * 1024 + col];
    if (c < chunk) pre = fmaxf(pre, pv);
    if (c > chunk) suf = fmaxf(suf, pv);
  }
  long r0 = (long)chunk * 64;
  const int cb = col & ~127, cw = col & 127;
  float run = pre;
  for (int i = 0; i < 64; i++) {
    long row = r0 + i;
    int xo = (int)(row & 15) << 3;
    int c0 = cb | (cw ^ xo);
    float v = x[row * 1024 + col];
    unsigned char* hr = h_in + row * 3072;
    hr[c0] = (unsigned char)f2e4m3(v);
    hr[1024 + c0] = (unsigned char)(row == 0 ? 0u : f2e4m3(run));
    run = fmaxf(run, v);
  }
  float run2 = suf;
  for (int i = 63; i >= 0; i--) {
    long row = r0 + i;
    int xo = (int)(row & 15) << 3;
    int c0 = cb | (cw ^ xo);
    float v = x[row * 1024 + col];
    h_in[row * 3072 + 2048 + c0] = (unsigned char)(row == 8191 ? 0u : f2e4m3(run2));
    run2 = fmaxf(run2, v);
  }
}

// ============ 256x256 FP8 GEMM1, BK=128 (r21: p1 barrier removed) ============
__global__ __launch_bounds__(512, 2) void gemm256_relu(
    const unsigned char* __restrict__ A, const unsigned char* __restrict__ B,
    unsigned char* __restrict__ C, const float* __restrict__ bias,
    const float* __restrict__ lnw, float* __restrict__ pp,
    int M, int N, int K) {
  extern __shared__ char smem[];
  const int NT = K >> 7;

  const int nwg = gridDim.x;
  const int cpx = nwg >> 3;
  const int bid = blockIdx.x;
  const int swz = (bid & 7) * cpx + (bid >> 3);
  const int tiles_m = M >> 8;
  const int tm = swz % tiles_m;
  const int tn = swz / tiles_m;
  const long brow = (long)tm * 256;
  const long bcol = (long)tn * 256;

  const int t = threadIdx.x;
  const int lane = t & 63, wv = t >> 6;
  const int wr = wv >> 2, wc = wv & 3;
  const int fr = lane & 15, fk = lane >> 4;

  const int srow = t >> 3;
  const int scol = (t & 7) * 16;
  const unsigned char* Asrc = A + (brow + srow) * (long)K + scol;
  const unsigned char* Bsrc = B + (bcol + srow) * (long)K + scol;
  const long hstep = (long)128 * K, lstep = (long)64 * K;

#define STAGE_A(j, reg, h, L)                                                   \
  __builtin_amdgcn_global_load_lds(AS1(Asrc + (h)*hstep + (L)*lstep + (j)*128), \
      AS3(smem + (reg)*32768 + (h)*16384 + (L)*8192 + t * 16), 16, 0, 0)
#define STAGE_B(j, h, L)                                                        \
  __builtin_amdgcn_global_load_lds(AS1(Bsrc + (h)*hstep + (L)*lstep + (j)*128), \
      AS3(smem + 98304 + ((j)&1) * 32768 + (h)*16384 + (L)*8192 + t * 16), 16, 0, 0)

  const int xr = fr << 3;
  const char* ArdRow = smem + (wr * 128 + fr) * 128;
  const char* BrdRow = smem + 98304 + (wc * 64 + fr) * 128;
#define RD_A(ar_, m, kk) \
  (*(const long*)(ArdRow + (ar_)*32768 + (m)*2048 + (((kk)*32 + fk * 8) ^ xr)))
#define RD_B(pb_, n, kk) \
  (*(const long*)(BrdRow + (pb_)*32768 + (n)*2048 + (((kk)*32 + fk * 8) ^ xr)))

#define MFMA_QUAD(mi, a_)                                                      \
  _Pragma("unroll")                                                            \
  for (int n = 0; n < 4; ++n) {                                                \
    _Pragma("unroll")                                                          \
    for (int kk = 0; kk < 4; ++kk)                                             \
      acc[(mi)][n] = __builtin_amdgcn_mfma_f32_16x16x32_fp8_fp8(               \
          a_[kk], bfr[n][kk], acc[(mi)][n], 0, 0, 0);                          \
  }

  f32x4 acc[8][4];
#pragma unroll
  for (int m = 0; m < 8; m++)
#pragma unroll
    for (int n = 0; n < 4; n++) acc[m][n] = (f32x4)0.f;

  STAGE_A(0, 0, 0, 0); STAGE_A(0, 0, 0, 1); STAGE_A(0, 0, 1, 0); STAGE_A(0, 0, 1, 1);
  STAGE_B(0, 0, 0); STAGE_B(0, 0, 1); STAGE_B(0, 1, 0); STAGE_B(0, 1, 1);
  STAGE_A(1, 1, 0, 0); STAGE_A(1, 1, 0, 1); STAGE_A(1, 1, 1, 0); STAGE_A(1, 1, 1, 1);
  STAGE_B(1, 0, 0); STAGE_B(1, 0, 1); STAGE_B(1, 1, 0); STAGE_B(1, 1, 1);
  asm volatile("s_waitcnt vmcnt(8)" ::: "memory");
  __builtin_amdgcn_s_barrier();

  long bfr[4][4];
  long ap[2][2][4];
  ap[0][0][0] = RD_A(0, 0, 0); ap[0][0][1] = RD_A(0, 0, 1);
  ap[0][0][2] = RD_A(0, 0, 2); ap[0][0][3] = RD_A(0, 0, 3);
  ap[0][1][0] = RD_A(0, 1, 0); ap[0][1][1] = RD_A(0, 1, 1);
  ap[0][1][2] = RD_A(0, 1, 2); ap[0][1][3] = RD_A(0, 1, 3);
#pragma unroll
  for (int n = 0; n < 4; ++n)
#pragma unroll
    for (int kk = 0; kk < 4; ++kk) bfr[n][kk] = RD_B(0, n, kk);

  int ar = 0;
  for (int g = 0; g < NT; ++g) {
    const int pb = g & 1;
    int sr = ar + 2; if (sr >= 3) sr -= 3;
    int nar = ar + 1; if (nar >= 3) nar = 0;
    const bool st = (g + 2 < NT);
#pragma unroll
    for (int p = 0; p < 4; ++p) {
      const int cs = p & 1, ns = cs ^ 1;
      asm volatile("s_waitcnt lgkmcnt(0)" ::: "memory");
      __builtin_amdgcn_sched_barrier(0);
      __builtin_amdgcn_s_setprio(1);
      MFMA_QUAD(2 * p, ap[cs][0])
      MFMA_QUAD(2 * p + 1, ap[cs][1])
      __builtin_amdgcn_s_setprio(0);
      if (p < 3) {
#pragma unroll
        for (int kk = 0; kk < 4; ++kk) {
          ap[ns][0][kk] = RD_A(ar, 2 * p + 2, kk);
          ap[ns][1][kk] = RD_A(ar, 2 * p + 3, kk);
        }
      } else if (g + 1 < NT) {
#pragma unroll
        for (int kk = 0; kk < 4; ++kk) {
          ap[ns][0][kk] = RD_A(nar, 0, kk);
          ap[ns][1][kk] = RD_A(nar, 1, kk);
        }
#pragma unroll
        for (int n = 0; n < 4; ++n)
#pragma unroll
          for (int kk = 0; kk < 4; ++kk) bfr[n][kk] = RD_B(pb ^ 1, n, kk);
      }
      if (st) {
        if (p == 0) { STAGE_A(g + 2, sr, 0, 0); STAGE_A(g + 2, sr, 0, 1); }
        if (p == 1) { STAGE_A(g + 2, sr, 1, 0); STAGE_A(g + 2, sr, 1, 1); }
        if (p == 2) { STAGE_B(g + 2, 0, 0); STAGE_B(g + 2, 0, 1); }
        if (p == 3) { STAGE_B(g + 2, 1, 0); STAGE_B(g + 2, 1, 1); }
      }
      if (p == 2 && g + 1 < NT) {
        if (st) asm volatile("s_waitcnt vmcnt(6)" ::: "memory");
        else    asm volatile("s_waitcnt vmcnt(0)" ::: "memory");
      }
      if (p != 1) asm volatile("s_barrier" ::: "memory");  // r21: p1 barrier dropped
    }
    ar = nar;
  }

  float bi[4], lw[4];
#pragma unroll
  for (int n = 0; n < 4; ++n) {
    const long col = bcol + wc * 64 + n * 16 + fr;
    bi[n] = bias[col];
    lw[n] = lnw[col];
  }
  float* sred = (float*)smem;
  float* qred = sred + 1024;
  const long orow = brow + wr * 128 + fk * 4;
  const int ocol = (int)bcol + wc * 64 + fr;
#pragma unroll
  for (int m = 0; m < 8; ++m) {
#pragma unroll
    for (int r = 0; r < 4; ++r) {
      const long row = orow + m * 16 + r;
      const int xo = ((fk * 4 + r) & 15) << 3;
      float s = 0.f, q = 0.f;
#pragma unroll
      for (int n = 0; n < 4; ++n) {
        float v = acc[m][n][r] * 0.03125f + bi[n];
        v = v > 0.f ? v : 0.f;
        s += v;
        q += v * v;
        const int col = ocol + n * 16;
        const int phys = (col & ~127) | ((col & 127) ^ xo);
        C[row * (long)N + phys] = (unsigned char)f2e4m3(v * lw[n]);
      }
#pragma unroll
      for (int off = 1; off < 16; off <<= 1) {
        s += __shfl_xor(s, off, 64);
        q += __shfl_xor(q, off, 64);
      }
      if (fr == 0) {
        int rl = wr * 128 + m * 16 + fk * 4 + r;
        sred[rl * 4 + wc] = s;
        qred[rl * 4 + wc] = q;
      }
    }
  }
  __syncthreads();
  if (t < 256) {
    float s = sred[t * 4] + sred[t * 4 + 1] + sred[t * 4 + 2] + sred[t * 4 + 3];
    float q = qred[t * 4] + qred[t * 4 + 1] + qred[t * 4 + 2] + qred[t * 4 + 3];
    float* pb = pp + (((long)(tm * 16 + tn) * 256 + t) * 2);
    pb[0] = s;
    pb[1] = q;
  }
#undef STAGE_A
#undef STAGE_B
#undef RD_A
#undef RD_B
#undef MFMA_QUAD
}

// ============ 256x128 FP8 GEMM2, BK=128 (r21: p1 barrier removed; stats fused) ============
__global__ __launch_bounds__(512, 2) void gemm256_g2(
    const unsigned char* __restrict__ A, const unsigned char* __restrict__ B,
    float* __restrict__ Cf, const float* __restrict__ bias,
    const float* __restrict__ gamma, const float* __restrict__ resid,
    const float* __restrict__ w2l, const float* __restrict__ b2l,
    const float* __restrict__ pp,
    int M, int N, int K) {
  extern __shared__ char smem[];
  const int NT = K >> 7;

  const int nwg = gridDim.x;
  const int cpx = nwg >> 3;
  const int bid = blockIdx.x;
  const int swz = (bid & 7) * cpx + (bid >> 3);
  const int tiles_m = M >> 8;
  const int tm = swz % tiles_m;
  const int tn = swz / tiles_m;
  const long brow = (long)tm * 256;
  const long bcol = (long)tn * 128;

  const int t = threadIdx.x;
  const int lane = t & 63, wv = t >> 6;
  const int wr = wv >> 1, wc = wv & 1;
  const int fr = lane & 15, fk = lane >> 4;

  const int srow = t >> 3;
  const int scol = (t & 7) * 16;
  const unsigned char* Asrc = A + (brow + srow) * (long)K + scol;
  const unsigned char* Bsrc = B + (bcol + srow) * (long)K + scol;
  const long hstep = (long)128 * K, lstep = (long)64 * K;

#define STAGE_A2(j, reg, h, L)                                                  \
  __builtin_amdgcn_global_load_lds(AS1(Asrc + (h)*hstep + (L)*lstep + (j)*128), \
      AS3(smem + (reg)*32768 + (h)*16384 + (L)*8192 + t * 16), 16, 0, 0)
#define STAGE_B2(j, L)                                                          \
  __builtin_amdgcn_global_load_lds(AS1(Bsrc + (L)*lstep + (j)*128),             \
      AS3(smem + 98304 + ((j)&1) * 16384 + (L)*8192 + t * 16), 16, 0, 0)

  const int xr = fr << 3;
  const char* ArdRow = smem + (wr * 64 + fr) * 128;
  const char* BrdRow = smem + 98304 + (wc * 64 + fr) * 128;
#define RD_A2(ar_, m, kk) \
  (*(const long*)(ArdRow + (ar_)*32768 + (m)*2048 + (((kk)*32 + fk * 8) ^ xr)))
#define RD_B2(pb_, n, kk) \
  (*(const long*)(BrdRow + (pb_)*16384 + (n)*2048 + (((kk)*32 + fk * 8) ^ xr)))

  f32x4 acc[4][4];
#pragma unroll
  for (int m = 0; m < 4; m++)
#pragma unroll
    for (int n = 0; n < 4; n++) acc[m][n] = (f32x4)0.f;

  STAGE_A2(0, 0, 0, 0); STAGE_A2(0, 0, 0, 1); STAGE_A2(0, 0, 1, 0); STAGE_A2(0, 0, 1, 1);
  STAGE_B2(0, 0); STAGE_B2(0, 1);
  STAGE_A2(1, 1, 0, 0); STAGE_A2(1, 1, 0, 1); STAGE_A2(1, 1, 1, 0); STAGE_A2(1, 1, 1, 1);
  STAGE_B2(1, 0); STAGE_B2(1, 1);
  asm volatile("s_waitcnt vmcnt(6)" ::: "memory");
  __builtin_amdgcn_s_barrier();

  long bfr[4][4];
  long ap[2][4];
  ap[0][0] = RD_A2(0, 0, 0); ap[0][1] = RD_A2(0, 0, 1);
  ap[0][2] = RD_A2(0, 0, 2); ap[0][3] = RD_A2(0, 0, 3);
#pragma unroll
  for (int n = 0; n < 4; ++n)
#pragma unroll
    for (int kk = 0; kk < 4; ++kk) bfr[n][kk] = RD_B2(0, n, kk);

  int ar = 0;
  for (int g = 0; g < NT; ++g) {
    const int pb = g & 1;
    int sr = ar + 2; if (sr >= 3) sr -= 3;
    int nar = ar + 1; if (nar >= 3) nar = 0;
    const bool st = (g + 2 < NT);
#pragma unroll
    for (int p = 0; p < 4; ++p) {
      const int cs = p & 1, ns = cs ^ 1;
      asm volatile("s_waitcnt lgkmcnt(0)" ::: "memory");
      __builtin_amdgcn_sched_barrier(0);
      __builtin_amdgcn_s_setprio(1);
#pragma unroll
      for (int n = 0; n < 4; ++n)
#pragma unroll
        for (int kk = 0; kk < 4; ++kk)
          acc[p][n] = __builtin_amdgcn_mfma_f32_16x16x32_fp8_fp8(
              ap[cs][kk], bfr[n][kk], acc[p][n], 0, 0, 0);
      __builtin_amdgcn_s_setprio(0);
      if (p < 3) {
#pragma unroll
        for (int kk = 0; kk < 4; ++kk) ap[ns][kk] = RD_A2(ar, p + 1, kk);
      } else if (g + 1 < NT) {
#pragma unroll
        for (int kk = 0; kk < 4; ++kk) ap[ns][kk] = RD_A2(nar, 0, kk);
#pragma unroll
        for (int n = 0; n < 4; ++n)
#pragma unroll
          for (int kk = 0; kk < 4; ++kk) bfr[n][kk] = RD_B2(pb ^ 1, n, kk);
      }
      if (st) {
        if (p == 0) { STAGE_A2(g + 2, sr, 0, 0); STAGE_A2(g + 2, sr, 0, 1); }
        if (p == 1) { STAGE_A2(g + 2, sr, 1, 0); STAGE_A2(g + 2, sr, 1, 1); }
        if (p == 2) { STAGE_B2(g + 2, 0); STAGE_B2(g + 2, 1); }
      }
      if (p == 2 && g + 1 < NT) {
        if (st) asm volatile("s_waitcnt vmcnt(6)" ::: "memory");
        else    asm volatile("s_waitcnt vmcnt(0)" ::: "memory");
      }
      if (p != 1) asm volatile("s_barrier" ::: "memory");  // r21: p1 barrier dropped
    }
    ar = nar;
  }

  // ---- row stats (LDS dead after final barrier) ----
  float* stats = (float*)smem;
  if (t < 256) {
    float s = 0.f, q = 0.f;
#pragma unroll
    for (int tb = 0; tb < 16; ++tb) {
      const float* p = pp + (((long)(tm * 16 + tb) * 256 + t) * 2);
      s += p[0];
      q += p[1];
    }
    float mu = s * (1.f / 4096.f);
    float var = q * (1.f / 4096.f) - mu * mu;
    stats[t * 2] = mu;
    stats[t * 2 + 1] = rsqrtf(var + 1e-6f);
  }
  __syncthreads();

  float bi[4], ga[4], wl[4], bl[4];
#pragma unroll
  for (int n = 0; n < 4; ++n) {
    const long col = bcol + wc * 64 + n * 16 + fr;
    bi[n] = bias[col];
    ga[n] = gamma[col];
    wl[n] = w2l[col];
    bl[n] = b2l[col];
  }
  const long orow = brow + wr * 64 + fk * 4;
  const long ocol = bcol + wc * 64 + fr;
  const int rl0 = wr * 64 + fk * 4;
#pragma unroll
  for (int m = 0; m < 4; ++m)
#pragma unroll
    for (int r = 0; r < 4; ++r) {
      const long row = orow + m * 16 + r;
      const int rl = rl0 + m * 16 + r;
      const float mu = stats[rl * 2];
      const float rs = stats[rl * 2 + 1];
#pragma unroll
      for (int n = 0; n < 4; ++n) {
        const long col = ocol + n * 16;
        float v = rs * (acc[m][n][r] * 0.03125f) - rs * mu * wl[n] + bl[n] + bi[n];
        Cf[row * (long)N + col] = v * ga[n] + resid[row * (long)N + col];
      }
    }
#undef STAGE_A2
#undef STAGE_B2
#undef RD_A2
#undef RD_B2
}

extern "C" void kernel_launch(void* const* d_in, const int* in_sizes, int n_in,
                              void* d_out, int out_size, void* d_ws, size_t ws_size,
                              hipStream_t stream) {
  const float* x     = (const float*)d_in[0];
  const float* W1    = (const float*)d_in[1];
  const float* b1    = (const float*)d_in[2];
  const float* ln_w  = (const float*)d_in[3];
  const float* ln_b  = (const float*)d_in[4];
  const float* W2    = (const float*)d_in[5];
  const float* b2    = (const float*)d_in[6];
  const float* gamma = (const float*)d_in[7];
  float* out = (float*)d_out;

  const int Nr = 8192, DIM = 1024, DFF = 4096, K1 = 3072;

  unsigned char* W1q   = (unsigned char*)d_ws;
  unsigned char* W2q   = W1q + (long)DFF * K1;
  unsigned char* h_in  = W2q + (long)DIM * DFF;
  unsigned char* h_act = h_in + (long)Nr * K1;
  float* partial = (float*)(h_act + (long)Nr * DFF);
  float* pp      = partial + 128 * 1024;
  float* w2l     = pp + 32 * 16 * 256 * 2;
  float* b2l     = w2l + DIM;

  hipFuncSetAttribute((const void*)gemm256_relu,
                      hipFuncAttributeMaxDynamicSharedMemorySize, 163840);
  hipFuncSetAttribute((const void*)gemm256_g2,
                      hipFuncAttributeMaxDynamicSharedMemorySize, 131072);

  prep<<<3584, 256, 0, stream>>>(W1, W1q, W2, W2q, x, partial, ln_w, ln_b, w2l, b2l);

  scan_emit<<<dim3(4, 128), 256, 0, stream>>>(x, partial, h_in);

  // GEMM1 (fp8 BK=128, A+B one-phase-ahead, 3 barriers/tile)
  gemm256_relu<<<512, 512, 163840, stream>>>(h_in, W1q, h_act, b1, ln_w, pp,
                                             Nr, DFF, K1);

  // GEMM2 (fp8 BK=128, stats fused)
  gemm256_g2<<<256, 512, 131072, stream>>>(h_act, W2q, out, b2, gamma, x,
                                           w2l, b2l, pp, Nr, DIM, DFF);
}